// Round 14
// baseline (4218.576 us; speedup 1.0000x reference)
//
#include <hip/hip_runtime.h>
#include <hip/hip_bf16.h>

#define BB 8
#define TT 2048
#define DD 512
#define LL 128
#define NC 16
#define ETH 512

typedef unsigned short u16;
typedef unsigned int u32;
typedef __attribute__((ext_vector_type(8))) short bf16x8v;
typedef __attribute__((ext_vector_type(4))) float f32x4v;

__device__ __forceinline__ float bf2f(u32 h) { return __uint_as_float(h << 16); }
__device__ __forceinline__ u16 f2bf(float f) {
    u32 u = __float_as_uint(f);
    u += 0x7fffu + ((u >> 16) & 1u);
    return (u16)(u >> 16);
}
__device__ __forceinline__ float wred64(float v) {
    #pragma unroll
    for (int off = 32; off; off >>= 1) v += __shfl_xor(v, off);
    return v;
}
__device__ __forceinline__ void unpack8(uint4 r, float* f) {
    f[0] = bf2f(r.x & 0xffff); f[1] = bf2f(r.x >> 16);
    f[2] = bf2f(r.y & 0xffff); f[3] = bf2f(r.y >> 16);
    f[4] = bf2f(r.z & 0xffff); f[5] = bf2f(r.z >> 16);
    f[6] = bf2f(r.w & 0xffff); f[7] = bf2f(r.w >> 16);
}

// ---------------- f32 -> bf16 convert ----------------
__global__ __launch_bounds__(256)
void f2bf_kernel(const float4* __restrict__ in, ushort4* __restrict__ out, const int n4)
{
    int i = blockIdx.x * 256 + threadIdx.x;
    const int stride = gridDim.x * 256;
    for (; i < n4; i += stride) {
        const float4 v = in[i];
        ushort4 o;
        o.x = f2bf(v.x); o.y = f2bf(v.y); o.z = f2bf(v.z); o.w = f2bf(v.w);
        out[i] = o;
    }
}

__global__ __launch_bounds__(256)
void wconv_kernel(const float4* __restrict__ Wq, const float4* __restrict__ Wk,
                  const float4* __restrict__ Wv, const float4* __restrict__ Wo,
                  ushort4* __restrict__ oq, ushort4* __restrict__ ok,
                  ushort4* __restrict__ ov, ushort4* __restrict__ oo)
{
    const int i = blockIdx.x * 256 + threadIdx.x;
    const int y = blockIdx.y;
    const float4* src = (y == 0) ? Wq : (y == 1) ? Wk : (y == 2) ? Wv : Wo;
    ushort4* dst = (y == 0) ? oq : (y == 1) ? ok : (y == 2) ? ov : oo;
    const float4 v = src[i];
    ushort4 o;
    o.x = f2bf(v.x); o.y = f2bf(v.y); o.z = f2bf(v.z); o.w = f2bf(v.w);
    dst[i] = o;
}

// ---------------- MFMA bf16 GEMM for projections (round-5 proven) ----------------
template<int OUT_BF>
__global__ __launch_bounds__(256)
void mfma_gemm(const u16* __restrict__ Abf, const u16* __restrict__ Bbf,
               const float* __restrict__ bias, void* __restrict__ Cout,
               const float outscale)
{
    __shared__ u16 Asm[128 * 64];
    __shared__ u16 Bsm[128 * 64];
    const int tid = threadIdx.x;
    const int wave = tid >> 6, lane = tid & 63;
    const int wm = wave >> 1, wn = wave & 1;
    const int m0 = blockIdx.x * 128, n0 = blockIdx.y * 128;

    f32x4v acc[4][4];
    #pragma unroll
    for (int i = 0; i < 4; ++i)
        #pragma unroll
        for (int j = 0; j < 4; ++j)
            acc[i][j] = (f32x4v){0.f, 0.f, 0.f, 0.f};

    const u16* gsrcA[4];
    const u16* gsrcB[4];
    #pragma unroll
    for (int i = 0; i < 4; ++i) {
        const int idx = i * 256 + tid;
        const int row = idx >> 3, c = idx & 7;
        const int kb = c ^ (row & 7);
        gsrcA[i] = Abf + (size_t)(m0 + row) * 512 + kb * 8;
        gsrcB[i] = Bbf + (size_t)(n0 + row) * 512 + kb * 8;
    }

    for (int k0 = 0; k0 < 512; k0 += 64) {
        __syncthreads();
        #pragma unroll
        for (int i = 0; i < 4; ++i) {
            __builtin_amdgcn_global_load_lds(
                (__attribute__((address_space(1))) void*)(gsrcA[i] + k0),
                (__attribute__((address_space(3))) void*)(Asm + (size_t)(i * 256 + wave * 64) * 8),
                16, 0, 0);
            __builtin_amdgcn_global_load_lds(
                (__attribute__((address_space(1))) void*)(gsrcB[i] + k0),
                (__attribute__((address_space(3))) void*)(Bsm + (size_t)(i * 256 + wave * 64) * 8),
                16, 0, 0);
        }
        asm volatile("s_waitcnt vmcnt(0)" ::: "memory");
        __syncthreads();

        const int l15 = lane & 15, lhi = lane >> 4;
        bf16x8v af[4][2], bfr[4][2];
        #pragma unroll
        for (int mf = 0; mf < 4; ++mf) {
            const int row = wm * 64 + mf * 16 + l15;
            const int sw = (row & 7) << 4;
            #pragma unroll
            for (int ks = 0; ks < 2; ++ks) {
                const int kbyte = ks * 64 + lhi * 16;
                af[mf][ks] = *(const bf16x8v*)((const char*)Asm + row * 128 + (kbyte ^ sw));
            }
        }
        #pragma unroll
        for (int nf = 0; nf < 4; ++nf) {
            const int row = wn * 64 + nf * 16 + l15;
            const int sw = (row & 7) << 4;
            #pragma unroll
            for (int ks = 0; ks < 2; ++ks) {
                const int kbyte = ks * 64 + lhi * 16;
                bfr[nf][ks] = *(const bf16x8v*)((const char*)Bsm + row * 128 + (kbyte ^ sw));
            }
        }
        #pragma unroll
        for (int ks = 0; ks < 2; ++ks)
            #pragma unroll
            for (int mf = 0; mf < 4; ++mf)
                #pragma unroll
                for (int nf = 0; nf < 4; ++nf)
                    acc[mf][nf] = __builtin_amdgcn_mfma_f32_16x16x32_bf16(
                        af[mf][ks], bfr[nf][ks], acc[mf][nf], 0, 0, 0);
    }
    const int l15 = lane & 15, lhi = lane >> 4;
    #pragma unroll
    for (int mf = 0; mf < 4; ++mf) {
        #pragma unroll
        for (int nf = 0; nf < 4; ++nf) {
            const int n = n0 + wn * 64 + nf * 16 + l15;
            const float bsv = bias[n];
            #pragma unroll
            for (int r = 0; r < 4; ++r) {
                const int m = m0 + wm * 64 + mf * 16 + lhi * 4 + r;
                const float val = (acc[mf][nf][r] + bsv) * outscale;
                if (OUT_BF) ((u16*)Cout)[(size_t)m * 512 + n] = f2bf(val);
                else        ((float*)Cout)[(size_t)m * 512 + n] = val;
            }
        }
    }
}

// ---------------- MFMA K6 body (256 thr, 4 waves): OBSA[:, n0..n0+127] ----------------
__device__ __forceinline__ void mfk6_body(const u16* __restrict__ Sb,
    const u16* __restrict__ Qt, const u16* __restrict__ AlT,
    const u16* __restrict__ Vnt, float* __restrict__ OBSA,
    float* __restrict__ dsum, const int m0, const int n0, const int bz)
{
    __shared__ u16 Ah[128 * 64];
    __shared__ u16 Bh[128 * 64];
    const int tid = threadIdx.x, wave = tid >> 6, lane = tid & 63;
    const int wm = wave >> 1, wn = wave & 1;

    f32x4v acc[4][4];
    #pragma unroll
    for (int i = 0; i < 4; ++i)
        #pragma unroll
        for (int j = 0; j < 4; ++j)
            acc[i][j] = (f32x4v){0.f, 0.f, 0.f, 0.f};

    const u16* Abase = Sb + (size_t)bz * 262144;
    const u16* Bbase = (n0 == 0) ? (Qt + (size_t)bz * 1048576)
                                 : (AlT + (size_t)bz * 65536);
    const u16* gA[4]; const u16* gB[4];
    #pragma unroll
    for (int i = 0; i < 4; ++i) {
        const int idx = i * 256 + tid, row = idx >> 3, c = idx & 7;
        const int kb = c ^ (row & 7);
        gA[i] = Abase + (size_t)(m0 + row) * 512 + kb * 8;
        gB[i] = Bbase + (size_t)row * 512 + kb * 8;
    }
    for (int k0 = 0; k0 < 512; k0 += 64) {
        __syncthreads();
        #pragma unroll
        for (int i = 0; i < 4; ++i) {
            const int dst = (i * 256 + wave * 64) * 8;
            __builtin_amdgcn_global_load_lds(
                (__attribute__((address_space(1))) void*)(gA[i] + k0),
                (__attribute__((address_space(3))) void*)(Ah + dst), 16, 0, 0);
            __builtin_amdgcn_global_load_lds(
                (__attribute__((address_space(1))) void*)(gB[i] + k0),
                (__attribute__((address_space(3))) void*)(Bh + dst), 16, 0, 0);
        }
        asm volatile("s_waitcnt vmcnt(0)" ::: "memory");
        __syncthreads();

        const int l15 = lane & 15, lhi = lane >> 4;
        bf16x8v af[4][2], bfr[4][2];
        #pragma unroll
        for (int mf = 0; mf < 4; ++mf) {
            const int row = wm * 64 + mf * 16 + l15, sw = (row & 7) << 4;
            #pragma unroll
            for (int ks = 0; ks < 2; ++ks) {
                const int kb2 = (ks * 64 + lhi * 16) ^ sw;
                af[mf][ks] = *(const bf16x8v*)((const char*)Ah + row * 128 + kb2);
            }
        }
        #pragma unroll
        for (int nf = 0; nf < 4; ++nf) {
            const int row = wn * 64 + nf * 16 + l15, sw = (row & 7) << 4;
            #pragma unroll
            for (int ks = 0; ks < 2; ++ks) {
                const int kb2 = (ks * 64 + lhi * 16) ^ sw;
                bfr[nf][ks] = *(const bf16x8v*)((const char*)Bh + row * 128 + kb2);
            }
        }
        #pragma unroll
        for (int ks = 0; ks < 2; ++ks)
            #pragma unroll
            for (int mf = 0; mf < 4; ++mf)
                #pragma unroll
                for (int nf = 0; nf < 4; ++nf)
                    acc[mf][nf] = __builtin_amdgcn_mfma_f32_16x16x32_bf16(
                        af[mf][ks], bfr[nf][ks], acc[mf][nf], 0, 0, 0);
    }
    const int l15 = lane & 15, lhi = lane >> 4;
    float* C = OBSA + (size_t)bz * 131072;
    #pragma unroll
    for (int mf = 0; mf < 4; ++mf)
        #pragma unroll
        for (int nf = 0; nf < 4; ++nf) {
            const int n = n0 + wn * 64 + nf * 16 + l15;
            #pragma unroll
            for (int r = 0; r < 4; ++r) {
                const int m = m0 + wm * 64 + mf * 16 + lhi * 4 + r;
                C[(size_t)m * 256 + n] = acc[mf][nf][r];
            }
        }
    if (n0 == 128) {
        const u16* Vn = Vnt + (size_t)bz * 1048576;
        #pragma unroll
        for (int nf = 0; nf < 4; ++nf) {
            const int n = n0 + wn * 64 + nf * 16 + l15;
            const int i2 = n - 128;
            float part = 0.f;
            #pragma unroll
            for (int mf = 0; mf < 4; ++mf) {
                const int m = m0 + wm * 64 + mf * 16 + lhi * 4;
                const ushort4 vr = *(const ushort4*)(Vn + (size_t)i2 * 512 + m);
                part += bf2f(vr.x) * acc[mf][nf][0] + bf2f(vr.y) * acc[mf][nf][1]
                      + bf2f(vr.z) * acc[mf][nf][2] + bf2f(vr.w) * acc[mf][nf][3];
            }
            part += __shfl_xor(part, 16);
            part += __shfl_xor(part, 32);
            if (lhi == 0) atomicAdd(dsum + bz * 128 + i2, part);
        }
    }
}

// ---------------- MFMA K6 Q-half body (512 thr, 8 waves, R11-proven): OB = S_bf x Q ----------------
__device__ __forceinline__ void mfk6q8_body(char* smemc,
    const u16* __restrict__ Sb, const u16* __restrict__ Qt,
    float* __restrict__ OBSA, const int bz)
{
    u16* Ah = (u16*)smemc;
    u16* Bh = (u16*)(smemc + 16384);
    const int tid = threadIdx.x, wave = tid >> 6, lane = tid & 63;
    const int wm = wave >> 1, wn = wave & 1;
    const int m0 = blockIdx.x * 128;

    f32x4v acc[2][4];
    #pragma unroll
    for (int i = 0; i < 2; ++i)
        #pragma unroll
        for (int j = 0; j < 4; ++j)
            acc[i][j] = (f32x4v){0.f, 0.f, 0.f, 0.f};

    const u16* Abase = Sb + (size_t)bz * 262144;
    const u16* Bbase = Qt + (size_t)bz * 1048576;
    const u16* gA[2]; const u16* gB[2];
    #pragma unroll
    for (int i = 0; i < 2; ++i) {
        const int idx = i * 512 + tid, row = idx >> 3, c = idx & 7;
        const int kb = c ^ (row & 7);
        gA[i] = Abase + (size_t)(m0 + row) * 512 + kb * 8;
        gB[i] = Bbase + (size_t)row * 512 + kb * 8;
    }
    for (int k0 = 0; k0 < 512; k0 += 64) {
        __syncthreads();
        #pragma unroll
        for (int i = 0; i < 2; ++i) {
            const int dst = (i * 512 + wave * 64) * 8;
            __builtin_amdgcn_global_load_lds(
                (__attribute__((address_space(1))) void*)(gA[i] + k0),
                (__attribute__((address_space(3))) void*)(Ah + dst), 16, 0, 0);
            __builtin_amdgcn_global_load_lds(
                (__attribute__((address_space(1))) void*)(gB[i] + k0),
                (__attribute__((address_space(3))) void*)(Bh + dst), 16, 0, 0);
        }
        asm volatile("s_waitcnt vmcnt(0)" ::: "memory");
        __syncthreads();

        const int l15 = lane & 15, lhi = lane >> 4;
        bf16x8v af[2][2], bfr[4][2];
        #pragma unroll
        for (int mf = 0; mf < 2; ++mf) {
            const int row = wm * 32 + mf * 16 + l15, sw = (row & 7) << 4;
            #pragma unroll
            for (int ks = 0; ks < 2; ++ks) {
                const int kb2 = (ks * 64 + lhi * 16) ^ sw;
                af[mf][ks] = *(const bf16x8v*)((const char*)Ah + row * 128 + kb2);
            }
        }
        #pragma unroll
        for (int nf = 0; nf < 4; ++nf) {
            const int row = wn * 64 + nf * 16 + l15, sw = (row & 7) << 4;
            #pragma unroll
            for (int ks = 0; ks < 2; ++ks) {
                const int kb2 = (ks * 64 + lhi * 16) ^ sw;
                bfr[nf][ks] = *(const bf16x8v*)((const char*)Bh + row * 128 + kb2);
            }
        }
        #pragma unroll
        for (int ks = 0; ks < 2; ++ks)
            #pragma unroll
            for (int mf = 0; mf < 2; ++mf)
                #pragma unroll
                for (int nf = 0; nf < 4; ++nf)
                    acc[mf][nf] = __builtin_amdgcn_mfma_f32_16x16x32_bf16(
                        af[mf][ks], bfr[nf][ks], acc[mf][nf], 0, 0, 0);
    }
    const int l15 = lane & 15, lhi = lane >> 4;
    float* C = OBSA + (size_t)bz * 131072;
    #pragma unroll
    for (int mf = 0; mf < 2; ++mf)
        #pragma unroll
        for (int nf = 0; nf < 4; ++nf) {
            const int n = wn * 64 + nf * 16 + l15;
            #pragma unroll
            for (int r = 0; r < 4; ++r) {
                const int m = m0 + wm * 32 + mf * 16 + lhi * 4 + r;
                C[(size_t)m * 256 + n] = acc[mf][nf][r];
            }
        }
}

// ---------------- Gv body (512 thr, R11-proven): Gv = Vn x Vn^T ----------------
__device__ __forceinline__ void gv512_body(char* smemc, const u16* __restrict__ Vnt,
    float* __restrict__ Gv, const int b)
{
    float (*As)[68] = (float(*)[68])smemc;
    float (*Bs)[68] = (float(*)[68])(smemc + 8704);
    const int tid = threadIdx.x;
    const int m0 = blockIdx.x * 64, n0 = blockIdx.y * 64;
    const u16* Vn = Vnt + (size_t)b * 1048576;
    const int tx = tid & 15, ty = tid >> 4;
    float acc[2][4] = {};
    for (int k0 = 0; k0 < 512; k0 += 32) {
        const int m = tid >> 3, k4 = (tid & 7) * 4;
        const ushort4 ra = *(const ushort4*)(Vn + (size_t)(m0 + m) * 512 + k0 + k4);
        As[k4][m]=bf2f(ra.x); As[k4+1][m]=bf2f(ra.y); As[k4+2][m]=bf2f(ra.z); As[k4+3][m]=bf2f(ra.w);
        const ushort4 rb = *(const ushort4*)(Vn + (size_t)(n0 + m) * 512 + k0 + k4);
        Bs[k4][m]=bf2f(rb.x); Bs[k4+1][m]=bf2f(rb.y); Bs[k4+2][m]=bf2f(rb.z); Bs[k4+3][m]=bf2f(rb.w);
        __syncthreads();
        #pragma unroll
        for (int kk = 0; kk < 32; ++kk) {
            const float a0 = As[kk][ty * 2], a1 = As[kk][ty * 2 + 1];
            const float4 bv = *(const float4*)&Bs[kk][tx * 4];
            acc[0][0] = fmaf(a0, bv.x, acc[0][0]);
            acc[0][1] = fmaf(a0, bv.y, acc[0][1]);
            acc[0][2] = fmaf(a0, bv.z, acc[0][2]);
            acc[0][3] = fmaf(a0, bv.w, acc[0][3]);
            acc[1][0] = fmaf(a1, bv.x, acc[1][0]);
            acc[1][1] = fmaf(a1, bv.y, acc[1][1]);
            acc[1][2] = fmaf(a1, bv.z, acc[1][2]);
            acc[1][3] = fmaf(a1, bv.w, acc[1][3]);
        }
        __syncthreads();
    }
    float* G = Gv + (size_t)b * 16384;
    #pragma unroll
    for (int i = 0; i < 2; ++i)
        #pragma unroll
        for (int j = 0; j < 4; ++j)
            G[(size_t)(m0 + ty * 2 + i) * 128 + n0 + tx * 4 + j] = acc[i][j];
}

// ---------------- elim2: factor (C -> global) + fused level-doubling inverse ----------------
// LDS: E(67584) reused as Tm; LpT/SpT/del reused as Scr (nj capped at 16 so
// Scr max = 5120 B). One kernel block does factor then inversion; C re-read
// from global (L1/L2-hot, each block touched once).
__device__ __forceinline__ void elim2_body(char* smemc,
    const float* __restrict__ G, float* __restrict__ Cg, float* __restrict__ Tg,
    const float* __restrict__ sseq, float* __restrict__ invd,
    float* __restrict__ ca, float* __restrict__ cb, const int t0, const int b)
{
    const int tid = threadIdx.x, lane = tid & 63, wave = tid >> 6;
    float (*E)[132]   = (float(*)[132])smemc;
    float (*LpT)[132] = (float(*)[132])(smemc + 67584);
    float (*SpT)[132] = (float(*)[132])(smemc + 71808);
    float* del        = (float*)(smemc + 76032);
    float (*Tm)[132]  = E;
    float* Scr        = (float*)(smemc + 67584);

    {
        const float4* Gb = (const float4*)(G + (size_t)b * 16384);
        for (int idx = tid; idx < 4096; idx += ETH) {
            const int r = idx >> 5, c4 = idx & 31;
            ((float4*)&E[r][0])[c4] = Gb[idx];
        }
    }
    __syncthreads();
    float* Cb = Cg + (size_t)b * 16384;

    for (int p = 0; p < 16; ++p) {
        const int pc0 = p * 8;
        if (wave == 0) {
            float pr0[8], pr1[8];
            #pragma unroll
            for (int j = 0; j < 8; ++j) {
                pr0[j] = E[pc0 + j][lane];
                pr1[j] = E[pc0 + j][64 + lane];
            }
            float dl[8];
            const bool hi = (pc0 >= 64);
            #pragma unroll
            for (int j = 0; j < 8; ++j) {
                const int t = pc0 + j;
                const int pl = t & 63;
                float prow[8];
                if (hi) {
                    #pragma unroll
                    for (int c = 0; c < 8; ++c) prow[c] = __shfl(pr1[c], pl);
                } else {
                    #pragma unroll
                    for (int c = 0; c < 8; ++c) prow[c] = __shfl(pr0[c], pl);
                }
                const float d = fmaxf(1.f + prow[j], 1e-6f);
                dl[j] = d;
                const float inv = 1.f / d;
                if (lane > t) {
                    const float coef = pr0[j] * inv;
                    #pragma unroll
                    for (int c = j + 1; c < 8; ++c) pr0[c] = fmaf(-coef, prow[c], pr0[c]);
                }
                if (lane + 64 > t) {
                    const float coef = pr1[j] * inv;
                    #pragma unroll
                    for (int c = j + 1; c < 8; ++c) pr1[c] = fmaf(-coef, prow[c], pr1[c]);
                }
            }
            #pragma unroll
            for (int j = 0; j < 8; ++j) {
                const float idj = 1.f / dl[j];
                const int t = pc0 + j;
                {
                    const bool below = (lane > t);
                    const float y = below ? pr0[j] : 0.f;
                    const float l = y * idj;
                    LpT[j][lane] = l; SpT[j][lane] = y;
                    Cb[(size_t)t * 128 + lane] = l;
                }
                {
                    const int r = lane + 64;
                    const bool below = (r > t);
                    const float y = below ? pr1[j] : 0.f;
                    const float l = y * idj;
                    LpT[j][r] = l; SpT[j][r] = y;
                    Cb[(size_t)t * 128 + r] = l;
                }
            }
            if (lane < 8) del[pc0 + lane] = dl[lane];
        }
        __syncthreads();
        const int r0b = pc0 + 8;
        if (r0b < 128) {
            const int nrows = 128 - r0b;
            const int c40 = r0b >> 2, nc4 = 32 - c40;
            for (int idx = tid; idx < nrows * nc4; idx += ETH) {
                const int rr = idx / nc4, cc = idx - rr * nc4;
                const int r = r0b + rr, c4 = c40 + cc;
                float4 e = ((float4*)&E[r][0])[c4];
                #pragma unroll
                for (int j = 0; j < 8; ++j) {
                    const float lv = LpT[j][r];
                    const float4 sv = ((const float4*)&SpT[j][0])[c4];
                    e.x = fmaf(-lv, sv.x, e.x);
                    e.y = fmaf(-lv, sv.y, e.y);
                    e.z = fmaf(-lv, sv.z, e.z);
                    e.w = fmaf(-lv, sv.w, e.w);
                }
                ((float4*)&E[r][0])[c4] = e;
            }
        }
        __syncthreads();
    }
    // consume del before Scr overwrites it
    if (tid < 128) {
        const float d = del[tid];
        const float s = sseq[(size_t)b * TT + t0 + tid];
        invd[b * 128 + tid] = 1.f / d;
        ca[b * 128 + tid] = s / d;
        cb[b * 128 + tid] = (tid == 127) ? s * 1e-6f : 0.f;
    }
    __syncthreads();

    // ---- inversion: Tm = (I+C)^-1, Tm aliases E, C from global ----
    for (int idx = tid; idx < 4224; idx += ETH)
        ((float4*)&Tm[0][0])[idx] = make_float4(0.f, 0.f, 0.f, 0.f);
    __syncthreads();
    if (tid < 128) Tm[tid][tid] = 1.f;
    __syncthreads();
    {
        const int g = tid >> 3, c = tid & 7;
        if (g < 16) {
            for (int r2 = c - 1; r2 >= 0; --r2) {
                float s = 0.f;
                for (int kk = r2 + 1; kk <= c; ++kk)
                    s = fmaf(Cb[(size_t)(8 * g + r2) * 128 + 8 * g + kk],
                             (kk == c) ? 1.f : Tm[8 * g + kk][8 * g + c], s);
                Tm[8 * g + r2][8 * g + c] = -s;
            }
        }
    }
    __syncthreads();
    for (int s = 8; s <= 64; s <<= 1) {
        const int npairs = 64 / s;
        const int nj = (s < 16) ? s : 16;
        const int stride = nj + 4;
        const int nj4 = nj >> 2;
        const int Nel = npairs * s * nj4;
        const int nhalf = s / nj;
        for (int jh = 0; jh < nhalf; ++jh) {
            for (int idx = tid; idx < Nel; idx += ETH) {
                const int p2 = idx / (s * nj4), rem = idx - p2 * s * nj4;
                const int i = rem / nj4, j4 = rem - i * nj4;
                const int I0 = 2 * s * p2, J0 = I0 + s;
                const int jc = jh * nj + j4 * 4;
                float4 x = make_float4(0.f, 0.f, 0.f, 0.f);
                for (int k = 0; k < s; ++k) {
                    const float cv = Cb[(size_t)(I0 + i) * 128 + J0 + k];
                    const float4 tv = *(const float4*)&Tm[J0 + k][J0 + jc];
                    x.x = fmaf(cv, tv.x, x.x);
                    x.y = fmaf(cv, tv.y, x.y);
                    x.z = fmaf(cv, tv.z, x.z);
                    x.w = fmaf(cv, tv.w, x.w);
                }
                *(float4*)&Scr[p2 * s * stride + i * stride + j4 * 4] = x;
            }
            __syncthreads();
            for (int idx = tid; idx < Nel; idx += ETH) {
                const int p2 = idx / (s * nj4), rem = idx - p2 * s * nj4;
                const int i = rem / nj4, j4 = rem - i * nj4;
                const int I0 = 2 * s * p2, J0 = I0 + s;
                const int jc = jh * nj + j4 * 4;
                float4 y = make_float4(0.f, 0.f, 0.f, 0.f);
                for (int k = 0; k < s; ++k) {
                    const float tv = Tm[I0 + i][I0 + k];
                    const float4 xv = *(const float4*)&Scr[p2 * s * stride + k * stride + j4 * 4];
                    y.x = fmaf(tv, xv.x, y.x);
                    y.y = fmaf(tv, xv.y, y.y);
                    y.z = fmaf(tv, xv.z, y.z);
                    y.w = fmaf(tv, xv.w, y.w);
                }
                float4 o;
                o.x = -y.x; o.y = -y.y; o.z = -y.z; o.w = -y.w;
                *(float4*)&Tm[I0 + i][J0 + jc] = o;
            }
            __syncthreads();
        }
    }
    {
        float4* Tgb = (float4*)(Tg + (size_t)b * 16384);
        for (int idx = tid; idx < 4096; idx += ETH) {
            const int r = idx >> 5, c4 = idx & 31;
            Tgb[idx] = ((const float4*)&Tm[r][0])[c4];
        }
    }
}

// ---------------- lvl3: elim2 (z<8) || Gv (z 8-15) || K6-Q (z 16-23) ----------------
__global__ __launch_bounds__(512)
void lvl3_kernel(const float* __restrict__ G, float* __restrict__ Cg,
                 float* __restrict__ Tg,
                 const float* __restrict__ sseq, float* __restrict__ invd,
                 float* __restrict__ ca, float* __restrict__ cb,
                 const u16* __restrict__ Vnt, const u16* __restrict__ Sb,
                 const u16* __restrict__ Qt, float* __restrict__ Gv,
                 float* __restrict__ OBSA, const int t0)
{
    __shared__ __align__(16) char smem[76800];
    const int z = blockIdx.z;
    if (z >= 16) {
        if (blockIdx.y != 0) return;
        mfk6q8_body(smem, Sb, Qt, OBSA, z - 16);
        return;
    }
    if (z >= 8) {
        if (blockIdx.x >= 2 || blockIdx.y >= 2) return;
        gv512_body(smem, Vnt, Gv, z - 8);
        return;
    }
    if (blockIdx.x != 0 || blockIdx.y != 0) return;
    elim2_body(smem, G, Cg, Tg, sseq, invd, ca, cb, t0, z);
}

// ---------------- prep: s_seq, Vn normalize ----------------
__global__ __launch_bounds__(256)
void prep_kernel(const u16* __restrict__ Qb, const u16* __restrict__ Ub,
                 u16* __restrict__ Vb, float* __restrict__ sseq)
{
    const int lane = threadIdx.x & 63, wid = threadIdx.x >> 6;
    const int row = blockIdx.x * 4 + wid;
    const size_t base = (size_t)row * DD;
    const uint4 qr = *(const uint4*)(Qb + base + lane * 8);
    const uint4 ur = *(const uint4*)(Ub + base + lane * 8);
    const uint4 vr = *(const uint4*)(Vb + base + lane * 8);
    float q[8], u[8], v[8];
    unpack8(qr, q); unpack8(ur, u); unpack8(vr, v);
    float sd = 0.f, nv = 0.f;
    #pragma unroll
    for (int e = 0; e < 8; ++e) { sd = fmaf(q[e], u[e], sd); nv = fmaf(v[e], v[e], nv); }
    #pragma unroll
    for (int off = 32; off; off >>= 1) { sd += __shfl_xor(sd, off); nv += __shfl_xor(nv, off); }
    if (lane == 0) sseq[row] = sd * 22.627416997969522f;
    const float inv = 1.f / (sqrtf(nv) + 1e-6f);
    uint4 o;
    o.x = (u32)f2bf(v[0] * inv) | ((u32)f2bf(v[1] * inv) << 16);
    o.y = (u32)f2bf(v[2] * inv) | ((u32)f2bf(v[3] * inv) << 16);
    o.z = (u32)f2bf(v[4] * inv) | ((u32)f2bf(v[5] * inv) << 16);
    o.w = (u32)f2bf(v[6] * inv) | ((u32)f2bf(v[7] * inv) << 16);
    *(uint4*)(Vb + base + lane * 8) = o;
}

__global__ __launch_bounds__(256)
void init_kernel(float4* __restrict__ A4, float4* __restrict__ S4,
                 ushort4* __restrict__ Sbf4, ushort4* __restrict__ Abf4,
                 float* __restrict__ SnSq, float* __restrict__ AnAcc)
{
    const int gtid = blockIdx.x * 256 + threadIdx.x;
    const int N4 = BB * DD * DD / 4;
    const ushort4 z4 = {0, 0, 0, 0};
    for (int idx = gtid; idx < N4; idx += gridDim.x * 256) {
        const int e0 = idx << 2;
        const int r = (e0 >> 9) & 511;
        const int c = e0 & 511;
        float4 v;
        v.x = (c + 0 == r) ? 1.f : 0.f;
        v.y = (c + 1 == r) ? 1.f : 0.f;
        v.z = (c + 2 == r) ? 1.f : 0.f;
        v.w = (c + 3 == r) ? 1.f : 0.f;
        A4[idx] = v;
        S4[idx] = make_float4(0.f, 0.f, 0.f, 0.f);
        Sbf4[idx] = z4;
        if (Abf4) {
            ushort4 a;
            a.x = (c + 0 == r) ? 0x3F80 : 0;
            a.y = (c + 1 == r) ? 0x3F80 : 0;
            a.z = (c + 2 == r) ? 0x3F80 : 0;
            a.w = (c + 3 == r) ? 0x3F80 : 0;
            Abf4[idx] = a;
        }
    }
    if (gtid < BB) { SnSq[gtid] = 0.f; AnAcc[gtid] = 512.f; }
}

// ---------------- MFMA K1: W = A_bf x U^T ----------------
__global__ __launch_bounds__(256)
void mfk1_kernel(const u16* __restrict__ Abf, const u16* __restrict__ Ut,
                 float* __restrict__ Wm)
{
    __shared__ u16 Ah[128 * 64];
    __shared__ u16 Bh[128 * 64];
    const int tid = threadIdx.x, wave = tid >> 6, lane = tid & 63;
    const int wm = wave >> 1, wn = wave & 1;
    const int m0 = blockIdx.x * 128;
    const int bz = blockIdx.z;

    f32x4v acc[4][4];
    #pragma unroll
    for (int i = 0; i < 4; ++i)
        #pragma unroll
        for (int j = 0; j < 4; ++j)
            acc[i][j] = (f32x4v){0.f, 0.f, 0.f, 0.f};

    const u16* Abase = Abf + (size_t)bz * 262144;
    const u16* Bbase = Ut + (size_t)bz * 1048576;
    const u16* gA[4]; const u16* gB[4];
    #pragma unroll
    for (int i = 0; i < 4; ++i) {
        const int idx = i * 256 + tid, row = idx >> 3, c = idx & 7;
        const int kb = c ^ (row & 7);
        gA[i] = Abase + (size_t)(m0 + row) * 512 + kb * 8;
        gB[i] = Bbase + (size_t)row * 512 + kb * 8;
    }
    for (int k0 = 0; k0 < 512; k0 += 64) {
        __syncthreads();
        #pragma unroll
        for (int i = 0; i < 4; ++i) {
            const int dst = (i * 256 + wave * 64) * 8;
            __builtin_amdgcn_global_load_lds(
                (__attribute__((address_space(1))) void*)(gA[i] + k0),
                (__attribute__((address_space(3))) void*)(Ah + dst), 16, 0, 0);
            __builtin_amdgcn_global_load_lds(
                (__attribute__((address_space(1))) void*)(gB[i] + k0),
                (__attribute__((address_space(3))) void*)(Bh + dst), 16, 0, 0);
        }
        asm volatile("s_waitcnt vmcnt(0)" ::: "memory");
        __syncthreads();

        const int l15 = lane & 15, lhi = lane >> 4;
        bf16x8v af[4][2], bfr[4][2];
        #pragma unroll
        for (int mf = 0; mf < 4; ++mf) {
            const int row = wm * 64 + mf * 16 + l15, sw = (row & 7) << 4;
            #pragma unroll
            for (int ks = 0; ks < 2; ++ks) {
                const int kb2 = (ks * 64 + lhi * 16) ^ sw;
                af[mf][ks] = *(const bf16x8v*)((const char*)Ah + row * 128 + kb2);
            }
        }
        #pragma unroll
        for (int nf = 0; nf < 4; ++nf) {
            const int row = wn * 64 + nf * 16 + l15, sw = (row & 7) << 4;
            #pragma unroll
            for (int ks = 0; ks < 2; ++ks) {
                const int kb2 = (ks * 64 + lhi * 16) ^ sw;
                bfr[nf][ks] = *(const bf16x8v*)((const char*)Bh + row * 128 + kb2);
            }
        }
        #pragma unroll
        for (int ks = 0; ks < 2; ++ks)
            #pragma unroll
            for (int mf = 0; mf < 4; ++mf)
                #pragma unroll
                for (int nf = 0; nf < 4; ++nf)
                    acc[mf][nf] = __builtin_amdgcn_mfma_f32_16x16x32_bf16(
                        af[mf][ks], bfr[nf][ks], acc[mf][nf], 0, 0, 0);
    }
    const int l15 = lane & 15, lhi = lane >> 4;
    float* C = Wm + (size_t)bz * 65536;
    #pragma unroll
    for (int mf = 0; mf < 4; ++mf)
        #pragma unroll
        for (int nf = 0; nf < 4; ++nf) {
            const int n = wn * 64 + nf * 16 + l15;
            #pragma unroll
            for (int r = 0; r < 4; ++r) {
                const int m = m0 + wm * 64 + mf * 16 + lhi * 4 + r;
                C[(size_t)m * 128 + n] = acc[mf][nf][r];
            }
        }
}

// ---------------- generic chunk GEMM ----------------
struct GP {
    int alay, blay, epi;
    const void* Ap; const void* Bp;
    void* Cp; float* Cio;
    const float* gdiag; float* anacc;
    const float* invdp; const float* cap; const float* cbp;
    const u16* Ulastp; float* Zsp; float* Alphap;
    u16* albt; u16* sbf; u16* abf;
    int lda, ldb, ldc, K;
    long sA, sB, sC, sCio;
};

__device__ __forceinline__ void gemm_body(const GP& p, const int bz) {
    __shared__ __align__(16) float As[32][68];
    __shared__ __align__(16) float Bs[32][68];
    const int m0 = blockIdx.x * 64, n0 = blockIdx.y * 64;
    const int tid = threadIdx.x, tx = tid & 15, ty = tid >> 4;
    float acc[4][4] = {};
    for (int k0 = 0; k0 < p.K; k0 += 32) {
        if (p.alay == 0) {
            const float* A = (const float*)p.Ap + (size_t)bz * p.sA;
            #pragma unroll
            for (int h = 0; h < 2; ++h) {
                const int g = tid + h * 256, m = g >> 3, k4 = (g & 7) * 4;
                const float4 r = *(const float4*)(A + (size_t)(m0 + m) * p.lda + k0 + k4);
                As[k4][m] = r.x; As[k4+1][m] = r.y; As[k4+2][m] = r.z; As[k4+3][m] = r.w;
            }
        } else if (p.alay == 2) {
            const u16* A = (const u16*)p.Ap + (size_t)bz * p.sA;
            #pragma unroll
            for (int h = 0; h < 2; ++h) {
                const int g = tid + h * 256, m = g >> 3, k4 = (g & 7) * 4;
                const ushort4 r = *(const ushort4*)(A + (size_t)(m0 + m) * p.lda + k0 + k4);
                As[k4][m]=bf2f(r.x); As[k4+1][m]=bf2f(r.y); As[k4+2][m]=bf2f(r.z); As[k4+3][m]=bf2f(r.w);
            }
        } else if (p.alay == 1 || p.alay == 4) {
            const float* A = (const float*)p.Ap + (size_t)bz * p.sA;
            #pragma unroll
            for (int h = 0; h < 2; ++h) {
                const int g = tid + h * 256, k = g >> 4, m4 = (g & 15) * 4;
                float4 r = *(const float4*)(A + (size_t)(k0 + k) * p.lda + m0 + m4);
                if (p.alay == 4) {
                    const int kg = k0 + k, mg = m0 + m4;
                    if (kg > mg + 0) r.x = 0.f;
                    if (kg > mg + 1) r.y = 0.f;
                    if (kg > mg + 2) r.z = 0.f;
                    if (kg > mg + 3) r.w = 0.f;
                }
                As[k][m4] = r.x; As[k][m4+1] = r.y; As[k][m4+2] = r.z; As[k][m4+3] = r.w;
            }
        } else { // 3
            const u16* A = (const u16*)p.Ap + (size_t)bz * p.sA;
            #pragma unroll
            for (int h = 0; h < 2; ++h) {
                const int g = tid + h * 256, k = g >> 4, m4 = (g & 15) * 4;
                const ushort4 r = *(const ushort4*)(A + (size_t)(k0 + k) * p.lda + m0 + m4);
                As[k][m4]=bf2f(r.x); As[k][m4+1]=bf2f(r.y); As[k][m4+2]=bf2f(r.z); As[k][m4+3]=bf2f(r.w);
            }
        }
        if (p.blay == 0) {
            const float* B = (const float*)p.Bp + (size_t)bz * p.sB;
            #pragma unroll
            for (int h = 0; h < 2; ++h) {
                const int g = tid + h * 256, k = g >> 4, n4 = (g & 15) * 4;
                const float4 r = *(const float4*)(B + (size_t)(k0 + k) * p.ldb + n0 + n4);
                Bs[k][n4] = r.x; Bs[k][n4+1] = r.y; Bs[k][n4+2] = r.z; Bs[k][n4+3] = r.w;
            }
        } else if (p.blay == 2) {
            const u16* B = (const u16*)p.Bp + (size_t)bz * p.sB;
            #pragma unroll
            for (int h = 0; h < 2; ++h) {
                const int g = tid + h * 256, k = g >> 4, n4 = (g & 15) * 4;
                const ushort4 r = *(const ushort4*)(B + (size_t)(k0 + k) * p.ldb + n0 + n4);
                Bs[k][n4]=bf2f(r.x); Bs[k][n4+1]=bf2f(r.y); Bs[k][n4+2]=bf2f(r.z); Bs[k][n4+3]=bf2f(r.w);
            }
        } else if (p.blay == 1) {
            const float* B = (const float*)p.Bp + (size_t)bz * p.sB;
            #pragma unroll
            for (int h = 0; h < 2; ++h) {
                const int g = tid + h * 256, n = g >> 3, k4 = (g & 7) * 4;
                const float4 r = *(const float4*)(B + (size_t)(n0 + n) * p.ldb + k0 + k4);
                Bs[k4][n] = r.x; Bs[k4+1][n] = r.y; Bs[k4+2][n] = r.z; Bs[k4+3][n] = r.w;
            }
        } else { // 3
            const u16* B = (const u16*)p.Bp + (size_t)bz * p.sB;
            #pragma unroll
            for (int h = 0; h < 2; ++h) {
                const int g = tid + h * 256, n = g >> 3, k4 = (g & 7) * 4;
                const ushort4 r = *(const ushort4*)(B + (size_t)(n0 + n) * p.ldb + k0 + k4);
                Bs[k4][n]=bf2f(r.x); Bs[k4+1][n]=bf2f(r.y); Bs[k4+2][n]=bf2f(r.z); Bs[k4+3][n]=bf2f(r.w);
            }
        }
        __syncthreads();
        #pragma unroll
        for (int kk = 0; kk < 32; ++kk) {
            const float4 xa = *(const float4*)&As[kk][ty * 4];
            const float4 wb = *(const float4*)&Bs[kk][tx * 4];
            const float xv[4] = {xa.x, xa.y, xa.z, xa.w};
            const float wv[4] = {wb.x, wb.y, wb.z, wb.w};
            #pragma unroll
            for (int i = 0; i < 4; ++i)
                #pragma unroll
                for (int j = 0; j < 4; ++j)
                    acc[i][j] = fmaf(xv[i], wv[j], acc[i][j]);
        }
        __syncthreads();
    }
    const int mb = m0 + ty * 4, nb = n0 + tx * 4;
    if (p.epi == 0) {
        float* C = (float*)p.Cp + (size_t)bz * p.sC;
        #pragma unroll
        for (int i = 0; i < 4; ++i)
            #pragma unroll
            for (int j = 0; j < 4; ++j)
                C[(size_t)(mb + i) * p.ldc + nb + j] = acc[i][j];
    } else if (p.epi == 1) {
        float* C = p.Cio + (size_t)bz * p.sCio;
        const float gd = p.gdiag[bz];
        float v2 = 0.f;
        #pragma unroll
        for (int i = 0; i < 4; ++i)
            #pragma unroll
            for (int j = 0; j < 4; ++j) {
                const size_t idx = (size_t)(mb + i) * p.ldc + nb + j;
                float v = C[idx] - acc[i][j] + ((mb + i) == (nb + j) ? gd : 0.f);
                C[idx] = v;
                if (p.abf) p.abf[(size_t)bz * p.sCio + idx] = f2bf(v);
                v2 = fmaf(v, v, v2);
            }
        v2 = wred64(v2);
        if ((tid & 63) == 0) atomicAdd(p.anacc + bz, v2);
    } else if (p.epi == 2) {
        float* C = p.Cio + (size_t)bz * p.sCio;
        u16* SB = p.sbf + (size_t)bz * p.sCio;
        #pragma unroll
        for (int i = 0; i < 4; ++i)
            #pragma unroll
            for (int j = 0; j < 4; ++j) {
                const size_t idx = (size_t)(mb + i) * p.ldc + nb + j;
                const float v = C[idx] + acc[i][j];
                C[idx] = v;
                SB[idx] = f2bf(v);
            }
    } else if (p.epi == 3) {
        u16* O = (u16*)p.Cp + (size_t)bz * p.sC;
        const float* OB = p.Cio + (size_t)bz * p.sCio;
        #pragma unroll
        for (int i = 0; i < 4; ++i)
            #pragma unroll
            for (int j = 0; j < 4; ++j)
                O[(size_t)(mb + i) * p.ldc + nb + j] =
                    f2bf(acc[i][j] + OB[(size_t)(nb + j) * 256 + mb + i]);
    } else { // 4: Z, Zs, Alpha f32 + AlphaT bf16
        float* Zb  = (float*)p.Cp + (size_t)bz * 65536;
        float* Zsb = p.Zsp + (size_t)bz * 65536;
        float* Apb = p.Alphap + (size_t)bz * 65536;
        #pragma unroll
        for (int j = 0; j < 4; ++j) {
            const int n = nb + j;
            const float iv = p.invdp[bz * 128 + n];
            const float cav = p.cap[bz * 128 + n];
            const float cbv = p.cbp[bz * 128 + n];
            #pragma unroll
            for (int i = 0; i < 4; ++i) {
                const int m = mb + i;
                const float z = acc[i][j];
                const size_t o = (size_t)m * 128 + n;
                Zb[o] = z;
                Zsb[o] = z * iv;
                float a = z * cav;
                if (cbv != 0.f) a = fmaf(cbv, bf2f(p.Ulastp[(size_t)bz * 1048576 + m]), a);
                Apb[o] = a;
                p.albt[(size_t)bz * 65536 + (size_t)n * 512 + m] = f2bf(a);
            }
        }
    }
}

__global__ __launch_bounds__(256) void gemmx(GP p) { gemm_body(p, blockIdx.z); }

// K2 wrapper: zeroes dsum (before any K6 atomics) then G = U^T W
__global__ __launch_bounds__(256)
void k2_kernel(GP p, float* __restrict__ dsum)
{
    if (blockIdx.x == 0 && blockIdx.y == 0 && threadIdx.x < 128)
        dsum[blockIdx.z * 128 + threadIdx.x] = 0.f;
    gemm_body(p, blockIdx.z);
}

// ---------------- lvl5c: K6-Alpha (+dsum) + P + Ga ----------------
__global__ __launch_bounds__(256)
void lvl5c_kernel(const u16* Sb, const u16* AlT, const float* Alpha,
                  const u16* Qt, const u16* Vnt,
                  float* P, float* Ga, float* OBSA, float* dsum)
{
    const int z = blockIdx.z;
    if (z < 8) {
        if (blockIdx.y != 0) return;
        mfk6_body(Sb, Qt, AlT, Vnt, OBSA, dsum, blockIdx.x * 128, 128, z);
        return;
    }
    if (blockIdx.x >= 2 || blockIdx.y >= 2) return;
    GP p{};
    p.K = 512; p.epi = 0; p.ldc = 128; p.sC = 16384;
    if (z < 16) {
        p.alay = 1; p.Ap = Alpha; p.lda = 128; p.sA = 65536;
        p.blay = 3; p.Bp = Qt; p.ldb = 512; p.sB = 1048576; p.Cp = P;
        gemm_body(p, z - 8);
    } else {
        p.alay = 1; p.Ap = Alpha; p.lda = 128; p.sA = 65536;
        p.blay = 0; p.Bp = Alpha; p.ldb = 128; p.sB = 65536; p.Cp = Ga;
        gemm_body(p, z - 16);
    }
}

// ---------------- merged level-7: K10 + K9 + K8 ----------------
__global__ __launch_bounds__(256)
void lvl7_kernel(const float* P, const u16* Vnt, u16* Obt, const float* OBSA,
                 const float* Alpha, const float* Zs, const float* Z,
                 float* S, u16* Sbf, float* A, u16* Abf,
                 const float* gdiag, float* AnAcc)
{
    const int z = blockIdx.z;
    GP p{};
    if (z < 8) {
        p.alay = 0; p.Ap = Zs; p.lda = 128; p.sA = 65536;
        p.blay = 1; p.Bp = Z; p.ldb = 128; p.sB = 65536;
        p.epi = 1; p.Cio = A; p.sCio = 262144; p.ldc = 512;
        p.gdiag = gdiag; p.anacc = AnAcc; p.abf = Abf; p.K = 128;
        gemm_body(p, z);
    } else if (z < 16) {
        p.alay = 3; p.Ap = Vnt; p.lda = 512; p.sA = 1048576;
        p.blay = 1; p.Bp = Alpha; p.ldb = 128; p.sB = 65536;
        p.epi = 2; p.Cio = S; p.sbf = Sbf; p.sCio = 262144; p.ldc = 512; p.K = 128;
        gemm_body(p, z - 8);
    } else {
        if (blockIdx.x >= 2) return;
        p.alay = 4; p.Ap = P; p.lda = 128; p.sA = 16384;
        p.blay = 2; p.Bp = Vnt; p.ldb = 512; p.sB = 1048576;
        p.epi = 3; p.Cp = Obt; p.ldc = 512; p.sC = 1048576;
        p.Cio = (float*)OBSA; p.sCio = 131072; p.K = 128;
        gemm_body(p, z - 16);
    }
}

// ---------------- guard ----------------
__global__ __launch_bounds__(256)
void guard_kernel(const float* __restrict__ dsum_g, const float* __restrict__ Ga,
                  const float* __restrict__ Gv, float* __restrict__ SnSq,
                  float* __restrict__ AnAcc, float* __restrict__ gdiag)
{
    const int b = blockIdx.x, tid = threadIdx.x;
    __shared__ float rpart[256], dsh[128], mdia[128];
    const int t = tid & 127, half = tid >> 7;
    const float* gv = Gv + (size_t)b * 16384 + t * 128;
    const float* ga = Ga + (size_t)b * 16384 + t * 128;
    float rs = 0.f;
    for (int j = half; j < t; j += 2) rs = fmaf(gv[j], ga[j], rs);
    rpart[tid] = rs;
    if (half == 0) { dsh[t] = dsum_g[b * 128 + t]; mdia[t] = gv[t] * ga[t]; }
    __syncthreads();
    if (tid == 0) {
        const float An2 = AnAcc[b];
        float Sn2 = SnSq[b], D = 0.f, T = 0.f;
        int ng = 0;
        for (int t2 = 0; t2 < 128; ++t2) {
            D += dsh[t2];
            T += mdia[t2] + 2.f * (rpart[t2] + rpart[t2 + 128]);
            const float sn2 = Sn2 + 2.f * D + T;
            if (sn2 > 1e6f || An2 > 1e6f) ++ng;
        }
        SnSq[b] = Sn2 + 2.f * D + T;
        gdiag[b] = 1e-6f + (float)ng * 1e-5f;
        AnAcc[b] = 0.f;
    }
}

extern "C" void kernel_launch(void* const* d_in, const int* in_sizes, int n_in,
                              void* d_out, int out_size, void* d_ws, size_t ws_size,
                              hipStream_t stream)
{
    const float* x  = (const float*)d_in[0];
    const float* Wq = (const float*)d_in[1];
    const float* bq = (const float*)d_in[2];
    const float* Wk = (const float*)d_in[3];
    const float* bk = (const float*)d_in[4];
    const float* Wv = (const float*)d_in[5];
    const float* bv = (const float*)d_in[6];
    const float* Wo = (const float*)d_in[7];
    const float* bo = (const float*)d_in[8];

    char* ws = (char*)d_ws;
    u16* Qb    = (u16*)(ws);
    u16* Ub    = (u16*)(ws + (16ull << 20));
    u16* Vnb   = (u16*)(ws + (32ull << 20));
    u16* Ob    = (u16*)(ws + (48ull << 20));   // also x_bf before chunk loop
    u16* x_bf  = Ob;
    float* A    = (float*)(ws + (64ull << 20));
    float* S    = (float*)(ws + (72ull << 20));
    float* Wm   = (float*)(ws + (80ull << 20));
    float* Z    = (float*)(ws + (82ull << 20));
    float* Zs   = (float*)(ws + (84ull << 20));
    float* Alpha= (float*)(ws + (86ull << 20));
    float* OBSA = (float*)(ws + (88ull << 20));
    float* G    = (float*)(ws + (92ull << 20));
    float* Tg   = (float*)(ws + (92ull << 20) + (512ull << 10));
    float* P    = (float*)(ws + (93ull << 20));
    float* Ga   = (float*)(ws + (93ull << 20) + (512ull << 10));
    float* Gv   = (float*)(ws + (94ull << 20));
    float* invd = (float*)(ws + (94ull << 20) + (512ull << 10));
    float* ca   = (float*)(ws + (94ull << 20) + (516ull << 10));
    float* cb   = (float*)(ws + (94ull << 20) + (520ull << 10));
    float* sseq = (float*)(ws + (94ull << 20) + (528ull << 10));
    float* SnSq = (float*)(ws + (94ull << 20) + (600ull << 10));
    float* AnAcc= (float*)(ws + (94ull << 20) + (600ull << 10) + 64);
    float* gdiag= (float*)(ws + (94ull << 20) + (600ull << 10) + 128);
    float* dsum = (float*)(ws + (94ull << 20) + (604ull << 10));
    u16* Wq_bf = (u16*)(ws + (95ull << 20));
    u16* Wk_bf = (u16*)(ws + (95ull << 20) + (512ull << 10));
    u16* Wv_bf = (u16*)(ws + (96ull << 20));
    u16* Wo_bf = (u16*)(ws + (96ull << 20) + (512ull << 10));
    u16* S_bf  = (u16*)(ws + (97ull << 20));   // 4 MiB bf16 mirror of S
    u16* AlT   = (u16*)(ws + (101ull << 20));  // 1 MiB AlphaT bf16

    const bool big = (ws_size >= (111ull << 20));
    u16* A_bf = big ? (u16*)(ws + (102ull << 20)) : (u16*)nullptr;  // 8 MiB
    float* Cg = big ? (float*)(ws + (110ull << 20)) : (float*)(ws + (102ull << 20)); // 512 KiB

    f2bf_kernel<<<2048, 256, 0, stream>>>((const float4*)x, (ushort4*)x_bf, 2097152);
    wconv_kernel<<<dim3(256, 4), 256, 0, stream>>>(
        (const float4*)Wq, (const float4*)Wk, (const float4*)Wv, (const float4*)Wo,
        (ushort4*)Wq_bf, (ushort4*)Wk_bf, (ushort4*)Wv_bf, (ushort4*)Wo_bf);

    mfma_gemm<1><<<dim3(128, 4), 256, 0, stream>>>(x_bf, Wq_bf, bq, Qb, 1.f);
    mfma_gemm<1><<<dim3(128, 4), 256, 0, stream>>>(x_bf, Wk_bf, bk, Ub, 0.04419417382415922f);
    mfma_gemm<1><<<dim3(128, 4), 256, 0, stream>>>(x_bf, Wv_bf, bv, Vnb, 1.f);
    prep_kernel<<<4096, 256, 0, stream>>>(Qb, Ub, Vnb, sseq);
    init_kernel<<<2048, 256, 0, stream>>>((float4*)A, (float4*)S, (ushort4*)S_bf,
                                          (ushort4*)A_bf, SnSq, AnAcc);

    for (int c = 0; c < NC; ++c) {
        const int t0 = c * LL;
        const u16* Ut = Ub + (size_t)t0 * 512;
        const u16* Qt = Qb + (size_t)t0 * 512;
        const u16* Vt = Vnb + (size_t)t0 * 512;
        // K1: W = A x U^T (MFMA via A_bf when workspace allows)
        if (big) {
            mfk1_kernel<<<dim3(4, 1, 8), 256, 0, stream>>>(A_bf, Ut, Wm);
        } else {
            GP p1{}; p1.alay = 0; p1.Ap = A; p1.lda = 512; p1.sA = 262144;
            p1.blay = 3; p1.Bp = Ut; p1.ldb = 512; p1.sB = 1048576;
            p1.epi = 0; p1.Cp = Wm; p1.ldc = 128; p1.sC = 65536; p1.K = 512;
            gemmx<<<dim3(8, 2, 8), 256, 0, stream>>>(p1);
        }
        // K2: G = U^T W  (+ zero dsum)
        GP p2{}; p2.alay = 2; p2.Ap = Ut; p2.lda = 512; p2.sA = 1048576;
        p2.blay = 0; p2.Bp = Wm; p2.ldb = 128; p2.sB = 65536;
        p2.epi = 0; p2.Cp = G; p2.ldc = 128; p2.sC = 16384; p2.K = 512;
        k2_kernel<<<dim3(2, 2, 8), 256, 0, stream>>>(p2, dsum);
        // lvl3: elim2 (factor+inv) || Gv || K6-Q (co-resident at 2 blocks/CU)
        lvl3_kernel<<<dim3(4, 2, 24), 512, 0, stream>>>(G, Cg, Tg, sseq, invd, ca, cb,
            Vt, S_bf, Qt, Gv, OBSA, t0);
        // p4: Z/Zs/Alpha (f32) + AlphaT (bf16) = W x T
        GP p4{}; p4.alay = 0; p4.Ap = Wm; p4.lda = 128; p4.sA = 65536;
        p4.blay = 0; p4.Bp = Tg; p4.ldb = 128; p4.sB = 16384;
        p4.epi = 4; p4.Cp = Z; p4.Zsp = Zs; p4.Alphap = Alpha; p4.albt = AlT;
        p4.invdp = invd; p4.cap = ca; p4.cbp = cb;
        p4.Ulastp = Ub + (size_t)(t0 + 127) * 512;
        p4.K = 128; p4.ldc = 128; p4.sC = 65536;
        gemmx<<<dim3(8, 2, 8), 256, 0, stream>>>(p4);
        // lvl5c: K6-Alpha (+dsum) + P + Ga
        lvl5c_kernel<<<dim3(4, 2, 24), 256, 0, stream>>>(S_bf, AlT, Alpha, Qt, Vt,
            P, Ga, OBSA, dsum);
        guard_kernel<<<8, 256, 0, stream>>>(dsum, Ga, Gv, SnSq, AnAcc, gdiag);
        // lvl7: K10 (A update + A_bf mirror) + K9 (S update + S_bf mirror) + K8 (O out)
        lvl7_kernel<<<dim3(8, 8, 24), 256, 0, stream>>>(P, Vt, Ob + (size_t)t0 * 512, OBSA,
            Alpha, Zs, Z, S, S_bf, A, A_bf, gdiag, AnAcc);
    }
    mfma_gemm<0><<<dim3(128, 4), 256, 0, stream>>>(Ob, Wo_bf, bo, d_out, 1.f);
}

// Round 15
// 3105.302 us; speedup vs baseline: 1.3585x; 1.3585x over previous
//
#include <hip/hip_runtime.h>
#include <hip/hip_bf16.h>

#define BB 8
#define TT 2048
#define DD 512
#define LL 128
#define NC 16
#define ETH 512

typedef unsigned short u16;
typedef unsigned int u32;
typedef __attribute__((ext_vector_type(8))) short bf16x8v;
typedef __attribute__((ext_vector_type(4))) float f32x4v;

__device__ __forceinline__ float bf2f(u32 h) { return __uint_as_float(h << 16); }
__device__ __forceinline__ u16 f2bf(float f) {
    u32 u = __float_as_uint(f);
    u += 0x7fffu + ((u >> 16) & 1u);
    return (u16)(u >> 16);
}
__device__ __forceinline__ float wred64(float v) {
    #pragma unroll
    for (int off = 32; off; off >>= 1) v += __shfl_xor(v, off);
    return v;
}
__device__ __forceinline__ void unpack8(uint4 r, float* f) {
    f[0] = bf2f(r.x & 0xffff); f[1] = bf2f(r.x >> 16);
    f[2] = bf2f(r.y & 0xffff); f[3] = bf2f(r.y >> 16);
    f[4] = bf2f(r.z & 0xffff); f[5] = bf2f(r.z >> 16);
    f[6] = bf2f(r.w & 0xffff); f[7] = bf2f(r.w >> 16);
}

// ---------------- f32 -> bf16 convert ----------------
__global__ __launch_bounds__(256)
void f2bf_kernel(const float4* __restrict__ in, ushort4* __restrict__ out, const int n4)
{
    int i = blockIdx.x * 256 + threadIdx.x;
    const int stride = gridDim.x * 256;
    for (; i < n4; i += stride) {
        const float4 v = in[i];
        ushort4 o;
        o.x = f2bf(v.x); o.y = f2bf(v.y); o.z = f2bf(v.z); o.w = f2bf(v.w);
        out[i] = o;
    }
}

__global__ __launch_bounds__(256)
void wconv_kernel(const float4* __restrict__ Wq, const float4* __restrict__ Wk,
                  const float4* __restrict__ Wv, const float4* __restrict__ Wo,
                  ushort4* __restrict__ oq, ushort4* __restrict__ ok,
                  ushort4* __restrict__ ov, ushort4* __restrict__ oo)
{
    const int i = blockIdx.x * 256 + threadIdx.x;
    const int y = blockIdx.y;
    const float4* src = (y == 0) ? Wq : (y == 1) ? Wk : (y == 2) ? Wv : Wo;
    ushort4* dst = (y == 0) ? oq : (y == 1) ? ok : (y == 2) ? ov : oo;
    const float4 v = src[i];
    ushort4 o;
    o.x = f2bf(v.x); o.y = f2bf(v.y); o.z = f2bf(v.z); o.w = f2bf(v.w);
    dst[i] = o;
}

// ---------------- MFMA bf16 GEMM for projections (round-5 proven) ----------------
template<int OUT_BF>
__global__ __launch_bounds__(256)
void mfma_gemm(const u16* __restrict__ Abf, const u16* __restrict__ Bbf,
               const float* __restrict__ bias, void* __restrict__ Cout,
               const float outscale)
{
    __shared__ u16 Asm[128 * 64];
    __shared__ u16 Bsm[128 * 64];
    const int tid = threadIdx.x;
    const int wave = tid >> 6, lane = tid & 63;
    const int wm = wave >> 1, wn = wave & 1;
    const int m0 = blockIdx.x * 128, n0 = blockIdx.y * 128;

    f32x4v acc[4][4];
    #pragma unroll
    for (int i = 0; i < 4; ++i)
        #pragma unroll
        for (int j = 0; j < 4; ++j)
            acc[i][j] = (f32x4v){0.f, 0.f, 0.f, 0.f};

    const u16* gsrcA[4];
    const u16* gsrcB[4];
    #pragma unroll
    for (int i = 0; i < 4; ++i) {
        const int idx = i * 256 + tid;
        const int row = idx >> 3, c = idx & 7;
        const int kb = c ^ (row & 7);
        gsrcA[i] = Abf + (size_t)(m0 + row) * 512 + kb * 8;
        gsrcB[i] = Bbf + (size_t)(n0 + row) * 512 + kb * 8;
    }

    for (int k0 = 0; k0 < 512; k0 += 64) {
        __syncthreads();
        #pragma unroll
        for (int i = 0; i < 4; ++i) {
            __builtin_amdgcn_global_load_lds(
                (__attribute__((address_space(1))) void*)(gsrcA[i] + k0),
                (__attribute__((address_space(3))) void*)(Asm + (size_t)(i * 256 + wave * 64) * 8),
                16, 0, 0);
            __builtin_amdgcn_global_load_lds(
                (__attribute__((address_space(1))) void*)(gsrcB[i] + k0),
                (__attribute__((address_space(3))) void*)(Bsm + (size_t)(i * 256 + wave * 64) * 8),
                16, 0, 0);
        }
        asm volatile("s_waitcnt vmcnt(0)" ::: "memory");
        __syncthreads();

        const int l15 = lane & 15, lhi = lane >> 4;
        bf16x8v af[4][2], bfr[4][2];
        #pragma unroll
        for (int mf = 0; mf < 4; ++mf) {
            const int row = wm * 64 + mf * 16 + l15;
            const int sw = (row & 7) << 4;
            #pragma unroll
            for (int ks = 0; ks < 2; ++ks) {
                const int kbyte = ks * 64 + lhi * 16;
                af[mf][ks] = *(const bf16x8v*)((const char*)Asm + row * 128 + (kbyte ^ sw));
            }
        }
        #pragma unroll
        for (int nf = 0; nf < 4; ++nf) {
            const int row = wn * 64 + nf * 16 + l15;
            const int sw = (row & 7) << 4;
            #pragma unroll
            for (int ks = 0; ks < 2; ++ks) {
                const int kbyte = ks * 64 + lhi * 16;
                bfr[nf][ks] = *(const bf16x8v*)((const char*)Bsm + row * 128 + (kbyte ^ sw));
            }
        }
        #pragma unroll
        for (int ks = 0; ks < 2; ++ks)
            #pragma unroll
            for (int mf = 0; mf < 4; ++mf)
                #pragma unroll
                for (int nf = 0; nf < 4; ++nf)
                    acc[mf][nf] = __builtin_amdgcn_mfma_f32_16x16x32_bf16(
                        af[mf][ks], bfr[nf][ks], acc[mf][nf], 0, 0, 0);
    }
    const int l15 = lane & 15, lhi = lane >> 4;
    #pragma unroll
    for (int mf = 0; mf < 4; ++mf) {
        #pragma unroll
        for (int nf = 0; nf < 4; ++nf) {
            const int n = n0 + wn * 64 + nf * 16 + l15;
            const float bsv = bias[n];
            #pragma unroll
            for (int r = 0; r < 4; ++r) {
                const int m = m0 + wm * 64 + mf * 16 + lhi * 4 + r;
                const float val = (acc[mf][nf][r] + bsv) * outscale;
                if (OUT_BF) ((u16*)Cout)[(size_t)m * 512 + n] = f2bf(val);
                else        ((float*)Cout)[(size_t)m * 512 + n] = val;
            }
        }
    }
}

// ---------------- MFMA K6 body (256 thr, 4 waves): OBSA = S_bf x [Q | AlphaT] ----------------
__device__ __forceinline__ void mfk6_body(const u16* __restrict__ Sb,
    const u16* __restrict__ Qt, const u16* __restrict__ AlT,
    const u16* __restrict__ Vnt, float* __restrict__ OBSA,
    float* __restrict__ dsum, const int bz)
{
    __shared__ u16 Ah[128 * 64];
    __shared__ u16 Bh[128 * 64];
    const int tid = threadIdx.x, wave = tid >> 6, lane = tid & 63;
    const int wm = wave >> 1, wn = wave & 1;
    const int m0 = blockIdx.x * 128, n0 = blockIdx.y * 128;

    f32x4v acc[4][4];
    #pragma unroll
    for (int i = 0; i < 4; ++i)
        #pragma unroll
        for (int j = 0; j < 4; ++j)
            acc[i][j] = (f32x4v){0.f, 0.f, 0.f, 0.f};

    const u16* Abase = Sb + (size_t)bz * 262144;
    const u16* Bbase = (n0 == 0) ? (Qt + (size_t)bz * 1048576)
                                 : (AlT + (size_t)bz * 65536);
    const u16* gA[4]; const u16* gB[4];
    #pragma unroll
    for (int i = 0; i < 4; ++i) {
        const int idx = i * 256 + tid, row = idx >> 3, c = idx & 7;
        const int kb = c ^ (row & 7);
        gA[i] = Abase + (size_t)(m0 + row) * 512 + kb * 8;
        gB[i] = Bbase + (size_t)row * 512 + kb * 8;
    }
    for (int k0 = 0; k0 < 512; k0 += 64) {
        __syncthreads();
        #pragma unroll
        for (int i = 0; i < 4; ++i) {
            const int dst = (i * 256 + wave * 64) * 8;
            __builtin_amdgcn_global_load_lds(
                (__attribute__((address_space(1))) void*)(gA[i] + k0),
                (__attribute__((address_space(3))) void*)(Ah + dst), 16, 0, 0);
            __builtin_amdgcn_global_load_lds(
                (__attribute__((address_space(1))) void*)(gB[i] + k0),
                (__attribute__((address_space(3))) void*)(Bh + dst), 16, 0, 0);
        }
        asm volatile("s_waitcnt vmcnt(0)" ::: "memory");
        __syncthreads();

        const int l15 = lane & 15, lhi = lane >> 4;
        bf16x8v af[4][2], bfr[4][2];
        #pragma unroll
        for (int mf = 0; mf < 4; ++mf) {
            const int row = wm * 64 + mf * 16 + l15, sw = (row & 7) << 4;
            #pragma unroll
            for (int ks = 0; ks < 2; ++ks) {
                const int kb2 = (ks * 64 + lhi * 16) ^ sw;
                af[mf][ks] = *(const bf16x8v*)((const char*)Ah + row * 128 + kb2);
            }
        }
        #pragma unroll
        for (int nf = 0; nf < 4; ++nf) {
            const int row = wn * 64 + nf * 16 + l15, sw = (row & 7) << 4;
            #pragma unroll
            for (int ks = 0; ks < 2; ++ks) {
                const int kb2 = (ks * 64 + lhi * 16) ^ sw;
                bfr[nf][ks] = *(const bf16x8v*)((const char*)Bh + row * 128 + kb2);
            }
        }
        #pragma unroll
        for (int ks = 0; ks < 2; ++ks)
            #pragma unroll
            for (int mf = 0; mf < 4; ++mf)
                #pragma unroll
                for (int nf = 0; nf < 4; ++nf)
                    acc[mf][nf] = __builtin_amdgcn_mfma_f32_16x16x32_bf16(
                        af[mf][ks], bfr[nf][ks], acc[mf][nf], 0, 0, 0);
    }
    const int l15 = lane & 15, lhi = lane >> 4;
    float* C = OBSA + (size_t)bz * 131072;
    #pragma unroll
    for (int mf = 0; mf < 4; ++mf)
        #pragma unroll
        for (int nf = 0; nf < 4; ++nf) {
            const int n = n0 + wn * 64 + nf * 16 + l15;
            #pragma unroll
            for (int r = 0; r < 4; ++r) {
                const int m = m0 + wm * 64 + mf * 16 + lhi * 4 + r;
                C[(size_t)m * 256 + n] = acc[mf][nf][r];
            }
        }
    if (n0 == 128) {
        const u16* Vn = Vnt + (size_t)bz * 1048576;
        #pragma unroll
        for (int nf = 0; nf < 4; ++nf) {
            const int n = n0 + wn * 64 + nf * 16 + l15;
            const int i2 = n - 128;
            float part = 0.f;
            #pragma unroll
            for (int mf = 0; mf < 4; ++mf) {
                const int m = m0 + wm * 64 + mf * 16 + lhi * 4;
                const ushort4 vr = *(const ushort4*)(Vn + (size_t)i2 * 512 + m);
                part += bf2f(vr.x) * acc[mf][nf][0] + bf2f(vr.y) * acc[mf][nf][1]
                      + bf2f(vr.z) * acc[mf][nf][2] + bf2f(vr.w) * acc[mf][nf][3];
            }
            part += __shfl_xor(part, 16);
            part += __shfl_xor(part, 32);
            if (lhi == 0) atomicAdd(dsum + bz * 128 + i2, part);
        }
    }
}

// ---------------- MFMA gram body (256 thr): C[128][128] = Arows x Brows^T, K=512 bf16 ----------------
__device__ __forceinline__ void mfg_body(const u16* __restrict__ Ab,
    const u16* __restrict__ Bb, float* __restrict__ Cq)
{
    __shared__ u16 Agh[128 * 64];
    __shared__ u16 Bgh[128 * 64];
    const int tid = threadIdx.x, wave = tid >> 6, lane = tid & 63;
    const int wm = wave >> 1, wn = wave & 1;

    f32x4v acc[4][4];
    #pragma unroll
    for (int i = 0; i < 4; ++i)
        #pragma unroll
        for (int j = 0; j < 4; ++j)
            acc[i][j] = (f32x4v){0.f, 0.f, 0.f, 0.f};

    const u16* gA[4]; const u16* gB[4];
    #pragma unroll
    for (int i = 0; i < 4; ++i) {
        const int idx = i * 256 + tid, row = idx >> 3, c = idx & 7;
        const int kb = c ^ (row & 7);
        gA[i] = Ab + (size_t)row * 512 + kb * 8;
        gB[i] = Bb + (size_t)row * 512 + kb * 8;
    }
    for (int k0 = 0; k0 < 512; k0 += 64) {
        __syncthreads();
        #pragma unroll
        for (int i = 0; i < 4; ++i) {
            const int dst = (i * 256 + wave * 64) * 8;
            __builtin_amdgcn_global_load_lds(
                (__attribute__((address_space(1))) void*)(gA[i] + k0),
                (__attribute__((address_space(3))) void*)(Agh + dst), 16, 0, 0);
            __builtin_amdgcn_global_load_lds(
                (__attribute__((address_space(1))) void*)(gB[i] + k0),
                (__attribute__((address_space(3))) void*)(Bgh + dst), 16, 0, 0);
        }
        asm volatile("s_waitcnt vmcnt(0)" ::: "memory");
        __syncthreads();

        const int l15 = lane & 15, lhi = lane >> 4;
        bf16x8v af[4][2], bfr[4][2];
        #pragma unroll
        for (int mf = 0; mf < 4; ++mf) {
            const int row = wm * 64 + mf * 16 + l15, sw = (row & 7) << 4;
            #pragma unroll
            for (int ks = 0; ks < 2; ++ks) {
                const int kb2 = (ks * 64 + lhi * 16) ^ sw;
                af[mf][ks] = *(const bf16x8v*)((const char*)Agh + row * 128 + kb2);
            }
        }
        #pragma unroll
        for (int nf = 0; nf < 4; ++nf) {
            const int row = wn * 64 + nf * 16 + l15, sw = (row & 7) << 4;
            #pragma unroll
            for (int ks = 0; ks < 2; ++ks) {
                const int kb2 = (ks * 64 + lhi * 16) ^ sw;
                bfr[nf][ks] = *(const bf16x8v*)((const char*)Bgh + row * 128 + kb2);
            }
        }
        #pragma unroll
        for (int ks = 0; ks < 2; ++ks)
            #pragma unroll
            for (int mf = 0; mf < 4; ++mf)
                #pragma unroll
                for (int nf = 0; nf < 4; ++nf)
                    acc[mf][nf] = __builtin_amdgcn_mfma_f32_16x16x32_bf16(
                        af[mf][ks], bfr[nf][ks], acc[mf][nf], 0, 0, 0);
    }
    const int l15 = lane & 15, lhi = lane >> 4;
    #pragma unroll
    for (int mf = 0; mf < 4; ++mf)
        #pragma unroll
        for (int nf = 0; nf < 4; ++nf) {
            const int n = wn * 64 + nf * 16 + l15;
            #pragma unroll
            for (int r = 0; r < 4; ++r) {
                const int m = wm * 64 + mf * 16 + lhi * 4 + r;
                Cq[(size_t)m * 128 + n] = acc[mf][nf][r];
            }
        }
}

// ---------------- MFMA K1: W = A_bf x U^T (M=512, N=128, K=512) ----------------
__global__ __launch_bounds__(256)
void mfk1_kernel(const u16* __restrict__ Abf, const u16* __restrict__ Ut,
                 float* __restrict__ Wm)
{
    __shared__ u16 Ah[128 * 64];
    __shared__ u16 Bh[128 * 64];
    const int tid = threadIdx.x, wave = tid >> 6, lane = tid & 63;
    const int wm = wave >> 1, wn = wave & 1;
    const int m0 = blockIdx.x * 128;
    const int bz = blockIdx.z;

    f32x4v acc[4][4];
    #pragma unroll
    for (int i = 0; i < 4; ++i)
        #pragma unroll
        for (int j = 0; j < 4; ++j)
            acc[i][j] = (f32x4v){0.f, 0.f, 0.f, 0.f};

    const u16* Abase = Abf + (size_t)bz * 262144;
    const u16* Bbase = Ut + (size_t)bz * 1048576;
    const u16* gA[4]; const u16* gB[4];
    #pragma unroll
    for (int i = 0; i < 4; ++i) {
        const int idx = i * 256 + tid, row = idx >> 3, c = idx & 7;
        const int kb = c ^ (row & 7);
        gA[i] = Abase + (size_t)(m0 + row) * 512 + kb * 8;
        gB[i] = Bbase + (size_t)row * 512 + kb * 8;
    }
    for (int k0 = 0; k0 < 512; k0 += 64) {
        __syncthreads();
        #pragma unroll
        for (int i = 0; i < 4; ++i) {
            const int dst = (i * 256 + wave * 64) * 8;
            __builtin_amdgcn_global_load_lds(
                (__attribute__((address_space(1))) void*)(gA[i] + k0),
                (__attribute__((address_space(3))) void*)(Ah + dst), 16, 0, 0);
            __builtin_amdgcn_global_load_lds(
                (__attribute__((address_space(1))) void*)(gB[i] + k0),
                (__attribute__((address_space(3))) void*)(Bh + dst), 16, 0, 0);
        }
        asm volatile("s_waitcnt vmcnt(0)" ::: "memory");
        __syncthreads();

        const int l15 = lane & 15, lhi = lane >> 4;
        bf16x8v af[4][2], bfr[4][2];
        #pragma unroll
        for (int mf = 0; mf < 4; ++mf) {
            const int row = wm * 64 + mf * 16 + l15, sw = (row & 7) << 4;
            #pragma unroll
            for (int ks = 0; ks < 2; ++ks) {
                const int kb2 = (ks * 64 + lhi * 16) ^ sw;
                af[mf][ks] = *(const bf16x8v*)((const char*)Ah + row * 128 + kb2);
            }
        }
        #pragma unroll
        for (int nf = 0; nf < 4; ++nf) {
            const int row = wn * 64 + nf * 16 + l15, sw = (row & 7) << 4;
            #pragma unroll
            for (int ks = 0; ks < 2; ++ks) {
                const int kb2 = (ks * 64 + lhi * 16) ^ sw;
                bfr[nf][ks] = *(const bf16x8v*)((const char*)Bh + row * 128 + kb2);
            }
        }
        #pragma unroll
        for (int ks = 0; ks < 2; ++ks)
            #pragma unroll
            for (int mf = 0; mf < 4; ++mf)
                #pragma unroll
                for (int nf = 0; nf < 4; ++nf)
                    acc[mf][nf] = __builtin_amdgcn_mfma_f32_16x16x32_bf16(
                        af[mf][ks], bfr[nf][ks], acc[mf][nf], 0, 0, 0);
    }
    const int l15 = lane & 15, lhi = lane >> 4;
    float* C = Wm + (size_t)bz * 65536;
    #pragma unroll
    for (int mf = 0; mf < 4; ++mf)
        #pragma unroll
        for (int nf = 0; nf < 4; ++nf) {
            const int n = wn * 64 + nf * 16 + l15;
            #pragma unroll
            for (int r = 0; r < 4; ++r) {
                const int m = m0 + wm * 64 + mf * 16 + lhi * 4 + r;
                C[(size_t)m * 128 + n] = acc[mf][nf][r];
            }
        }
}

// ---------------- prep: s_seq, Vn normalize ----------------
__global__ __launch_bounds__(256)
void prep_kernel(const u16* __restrict__ Qb, const u16* __restrict__ Ub,
                 u16* __restrict__ Vb, float* __restrict__ sseq)
{
    const int lane = threadIdx.x & 63, wid = threadIdx.x >> 6;
    const int row = blockIdx.x * 4 + wid;
    const size_t base = (size_t)row * DD;
    const uint4 qr = *(const uint4*)(Qb + base + lane * 8);
    const uint4 ur = *(const uint4*)(Ub + base + lane * 8);
    const uint4 vr = *(const uint4*)(Vb + base + lane * 8);
    float q[8], u[8], v[8];
    unpack8(qr, q); unpack8(ur, u); unpack8(vr, v);
    float sd = 0.f, nv = 0.f;
    #pragma unroll
    for (int e = 0; e < 8; ++e) { sd = fmaf(q[e], u[e], sd); nv = fmaf(v[e], v[e], nv); }
    #pragma unroll
    for (int off = 32; off; off >>= 1) { sd += __shfl_xor(sd, off); nv += __shfl_xor(nv, off); }
    if (lane == 0) sseq[row] = sd * 22.627416997969522f;
    const float inv = 1.f / (sqrtf(nv) + 1e-6f);
    uint4 o;
    o.x = (u32)f2bf(v[0] * inv) | ((u32)f2bf(v[1] * inv) << 16);
    o.y = (u32)f2bf(v[2] * inv) | ((u32)f2bf(v[3] * inv) << 16);
    o.z = (u32)f2bf(v[4] * inv) | ((u32)f2bf(v[5] * inv) << 16);
    o.w = (u32)f2bf(v[6] * inv) | ((u32)f2bf(v[7] * inv) << 16);
    *(uint4*)(Vb + base + lane * 8) = o;
}

__global__ __launch_bounds__(256)
void init_kernel(float4* __restrict__ A4, float4* __restrict__ S4,
                 ushort4* __restrict__ Sbf4, ushort4* __restrict__ Abf4,
                 float* __restrict__ SnSq, float* __restrict__ AnAcc)
{
    const int gtid = blockIdx.x * 256 + threadIdx.x;
    const int N4 = BB * DD * DD / 4;
    const ushort4 z4 = {0, 0, 0, 0};
    for (int idx = gtid; idx < N4; idx += gridDim.x * 256) {
        const int e0 = idx << 2;
        const int r = (e0 >> 9) & 511;
        const int c = e0 & 511;
        float4 v;
        v.x = (c + 0 == r) ? 1.f : 0.f;
        v.y = (c + 1 == r) ? 1.f : 0.f;
        v.z = (c + 2 == r) ? 1.f : 0.f;
        v.w = (c + 3 == r) ? 1.f : 0.f;
        A4[idx] = v;
        S4[idx] = make_float4(0.f, 0.f, 0.f, 0.f);
        Sbf4[idx] = z4;
        if (Abf4) {
            ushort4 a;
            a.x = (c + 0 == r) ? 0x3F80 : 0;
            a.y = (c + 1 == r) ? 0x3F80 : 0;
            a.z = (c + 2 == r) ? 0x3F80 : 0;
            a.w = (c + 3 == r) ? 0x3F80 : 0;
            Abf4[idx] = a;
        }
    }
    if (gtid < BB) { SnSq[gtid] = 0.f; AnAcc[gtid] = 512.f; }
}

// ---------------- generic chunk GEMM ----------------
struct GP {
    int alay, blay, epi;
    const void* Ap; const void* Bp;
    void* Cp; float* Cio;
    const float* gdiag; float* anacc;
    const float* invdp; const float* cap; const float* cbp;
    const u16* Ulastp; float* Zsp; float* Alphap;
    u16* albt; u16* sbf; u16* abf;
    int lda, ldb, ldc, K;
    long sA, sB, sC, sCio;
};

__device__ __forceinline__ void gemm_body(const GP& p, const int bz) {
    __shared__ __align__(16) float As[32][68];
    __shared__ __align__(16) float Bs[32][68];
    const int m0 = blockIdx.x * 64, n0 = blockIdx.y * 64;
    const int tid = threadIdx.x, tx = tid & 15, ty = tid >> 4;
    float acc[4][4] = {};
    for (int k0 = 0; k0 < p.K; k0 += 32) {
        if (p.alay == 0) {
            const float* A = (const float*)p.Ap + (size_t)bz * p.sA;
            #pragma unroll
            for (int h = 0; h < 2; ++h) {
                const int g = tid + h * 256, m = g >> 3, k4 = (g & 7) * 4;
                const float4 r = *(const float4*)(A + (size_t)(m0 + m) * p.lda + k0 + k4);
                As[k4][m] = r.x; As[k4+1][m] = r.y; As[k4+2][m] = r.z; As[k4+3][m] = r.w;
            }
        } else if (p.alay == 2) {
            const u16* A = (const u16*)p.Ap + (size_t)bz * p.sA;
            #pragma unroll
            for (int h = 0; h < 2; ++h) {
                const int g = tid + h * 256, m = g >> 3, k4 = (g & 7) * 4;
                const ushort4 r = *(const ushort4*)(A + (size_t)(m0 + m) * p.lda + k0 + k4);
                As[k4][m]=bf2f(r.x); As[k4+1][m]=bf2f(r.y); As[k4+2][m]=bf2f(r.z); As[k4+3][m]=bf2f(r.w);
            }
        } else if (p.alay == 1 || p.alay == 4) {
            const float* A = (const float*)p.Ap + (size_t)bz * p.sA;
            #pragma unroll
            for (int h = 0; h < 2; ++h) {
                const int g = tid + h * 256, k = g >> 4, m4 = (g & 15) * 4;
                float4 r = *(const float4*)(A + (size_t)(k0 + k) * p.lda + m0 + m4);
                if (p.alay == 4) {
                    const int kg = k0 + k, mg = m0 + m4;
                    if (kg > mg + 0) r.x = 0.f;
                    if (kg > mg + 1) r.y = 0.f;
                    if (kg > mg + 2) r.z = 0.f;
                    if (kg > mg + 3) r.w = 0.f;
                }
                As[k][m4] = r.x; As[k][m4+1] = r.y; As[k][m4+2] = r.z; As[k][m4+3] = r.w;
            }
        } else { // 3
            const u16* A = (const u16*)p.Ap + (size_t)bz * p.sA;
            #pragma unroll
            for (int h = 0; h < 2; ++h) {
                const int g = tid + h * 256, k = g >> 4, m4 = (g & 15) * 4;
                const ushort4 r = *(const ushort4*)(A + (size_t)(k0 + k) * p.lda + m0 + m4);
                As[k][m4]=bf2f(r.x); As[k][m4+1]=bf2f(r.y); As[k][m4+2]=bf2f(r.z); As[k][m4+3]=bf2f(r.w);
            }
        }
        if (p.blay == 0) {
            const float* B = (const float*)p.Bp + (size_t)bz * p.sB;
            #pragma unroll
            for (int h = 0; h < 2; ++h) {
                const int g = tid + h * 256, k = g >> 4, n4 = (g & 15) * 4;
                const float4 r = *(const float4*)(B + (size_t)(k0 + k) * p.ldb + n0 + n4);
                Bs[k][n4] = r.x; Bs[k][n4+1] = r.y; Bs[k][n4+2] = r.z; Bs[k][n4+3] = r.w;
            }
        } else if (p.blay == 2) {
            const u16* B = (const u16*)p.Bp + (size_t)bz * p.sB;
            #pragma unroll
            for (int h = 0; h < 2; ++h) {
                const int g = tid + h * 256, k = g >> 4, n4 = (g & 15) * 4;
                const ushort4 r = *(const ushort4*)(B + (size_t)(k0 + k) * p.ldb + n0 + n4);
                Bs[k][n4]=bf2f(r.x); Bs[k][n4+1]=bf2f(r.y); Bs[k][n4+2]=bf2f(r.z); Bs[k][n4+3]=bf2f(r.w);
            }
        } else if (p.blay == 1) {
            const float* B = (const float*)p.Bp + (size_t)bz * p.sB;
            #pragma unroll
            for (int h = 0; h < 2; ++h) {
                const int g = tid + h * 256, n = g >> 3, k4 = (g & 7) * 4;
                const float4 r = *(const float4*)(B + (size_t)(n0 + n) * p.ldb + k0 + k4);
                Bs[k4][n] = r.x; Bs[k4+1][n] = r.y; Bs[k4+2][n] = r.z; Bs[k4+3][n] = r.w;
            }
        } else { // 3
            const u16* B = (const u16*)p.Bp + (size_t)bz * p.sB;
            #pragma unroll
            for (int h = 0; h < 2; ++h) {
                const int g = tid + h * 256, n = g >> 3, k4 = (g & 7) * 4;
                const ushort4 r = *(const ushort4*)(B + (size_t)(n0 + n) * p.ldb + k0 + k4);
                Bs[k4][n]=bf2f(r.x); Bs[k4+1][n]=bf2f(r.y); Bs[k4+2][n]=bf2f(r.z); Bs[k4+3][n]=bf2f(r.w);
            }
        }
        __syncthreads();
        #pragma unroll
        for (int kk = 0; kk < 32; ++kk) {
            const float4 xa = *(const float4*)&As[kk][ty * 4];
            const float4 wb = *(const float4*)&Bs[kk][tx * 4];
            const float xv[4] = {xa.x, xa.y, xa.z, xa.w};
            const float wv[4] = {wb.x, wb.y, wb.z, wb.w};
            #pragma unroll
            for (int i = 0; i < 4; ++i)
                #pragma unroll
                for (int j = 0; j < 4; ++j)
                    acc[i][j] = fmaf(xv[i], wv[j], acc[i][j]);
        }
        __syncthreads();
    }
    const int mb = m0 + ty * 4, nb = n0 + tx * 4;
    if (p.epi == 0) {
        float* C = (float*)p.Cp + (size_t)bz * p.sC;
        #pragma unroll
        for (int i = 0; i < 4; ++i)
            #pragma unroll
            for (int j = 0; j < 4; ++j)
                C[(size_t)(mb + i) * p.ldc + nb + j] = acc[i][j];
    } else if (p.epi == 1) {
        float* C = p.Cio + (size_t)bz * p.sCio;
        const float gd = p.gdiag[bz];
        float v2 = 0.f;
        #pragma unroll
        for (int i = 0; i < 4; ++i)
            #pragma unroll
            for (int j = 0; j < 4; ++j) {
                const size_t idx = (size_t)(mb + i) * p.ldc + nb + j;
                float v = C[idx] - acc[i][j] + ((mb + i) == (nb + j) ? gd : 0.f);
                C[idx] = v;
                if (p.abf) p.abf[(size_t)bz * p.sCio + idx] = f2bf(v);
                v2 = fmaf(v, v, v2);
            }
        v2 = wred64(v2);
        if ((tid & 63) == 0) atomicAdd(p.anacc + bz, v2);
    } else if (p.epi == 2) {
        float* C = p.Cio + (size_t)bz * p.sCio;
        u16* SB = p.sbf + (size_t)bz * p.sCio;
        #pragma unroll
        for (int i = 0; i < 4; ++i)
            #pragma unroll
            for (int j = 0; j < 4; ++j) {
                const size_t idx = (size_t)(mb + i) * p.ldc + nb + j;
                const float v = C[idx] + acc[i][j];
                C[idx] = v;
                SB[idx] = f2bf(v);
            }
    } else if (p.epi == 3) {
        u16* O = (u16*)p.Cp + (size_t)bz * p.sC;
        const float* OB = p.Cio + (size_t)bz * p.sCio;
        #pragma unroll
        for (int i = 0; i < 4; ++i)
            #pragma unroll
            for (int j = 0; j < 4; ++j)
                O[(size_t)(mb + i) * p.ldc + nb + j] =
                    f2bf(acc[i][j] + OB[(size_t)(nb + j) * 256 + mb + i]);
    } else { // 4: Z, Zs, Alpha f32 + AlphaT bf16
        float* Zb  = (float*)p.Cp + (size_t)bz * 65536;
        float* Zsb = p.Zsp + (size_t)bz * 65536;
        float* Apb = p.Alphap + (size_t)bz * 65536;
        #pragma unroll
        for (int j = 0; j < 4; ++j) {
            const int n = nb + j;
            const float iv = p.invdp[bz * 128 + n];
            const float cav = p.cap[bz * 128 + n];
            const float cbv = p.cbp[bz * 128 + n];
            #pragma unroll
            for (int i = 0; i < 4; ++i) {
                const int m = mb + i;
                const float z = acc[i][j];
                const size_t o = (size_t)m * 128 + n;
                Zb[o] = z;
                Zsb[o] = z * iv;
                float a = z * cav;
                if (cbv != 0.f) a = fmaf(cbv, bf2f(p.Ulastp[(size_t)bz * 1048576 + m]), a);
                Apb[o] = a;
                p.albt[(size_t)bz * 65536 + (size_t)n * 512 + m] = f2bf(a);
            }
        }
    }
}

__global__ __launch_bounds__(256) void gemmx(GP p) { gemm_body(p, blockIdx.z); }

// ---------------- merged level-5: MFMA K6 + MFMA gram3 (P, Ga, Gv) ----------------
__global__ __launch_bounds__(256)
void lvl5_kernel(const u16* Sb, const u16* AlT, const float* Alpha,
                 const u16* Qt, const u16* Vnt,
                 float* P, float* Ga, float* Gv, float* OBSA, float* dsum)
{
    const int z = blockIdx.z;
    if (z < 8) {
        mfk6_body(Sb, Qt, AlT, Vnt, OBSA, dsum, z);
        return;
    }
    if (blockIdx.x != 0 || blockIdx.y != 0) return;
    const int zz = z - 8, b = zz / 3, j = zz - b * 3;
    const u16* Ab = (j == 2) ? (Vnt + (size_t)b * 1048576) : (AlT + (size_t)b * 65536);
    const u16* Bb = (j == 0) ? (Qt + (size_t)b * 1048576)
                  : (j == 1) ? (AlT + (size_t)b * 65536)
                             : (Vnt + (size_t)b * 1048576);
    float* Cq = ((j == 0) ? P : (j == 1) ? Ga : Gv) + (size_t)b * 16384;
    mfg_body(Ab, Bb, Cq);
}

// ---------------- merged level-7: K10 + K9 + K8 ----------------
__global__ __launch_bounds__(256)
void lvl7_kernel(const float* P, const u16* Vnt, u16* Obt, const float* OBSA,
                 const float* Alpha, const float* Zs, const float* Z,
                 float* S, u16* Sbf, float* A, u16* Abf,
                 const float* gdiag, float* AnAcc)
{
    const int z = blockIdx.z;
    GP p{};
    if (z < 8) {
        p.alay = 0; p.Ap = Zs; p.lda = 128; p.sA = 65536;
        p.blay = 1; p.Bp = Z; p.ldb = 128; p.sB = 65536;
        p.epi = 1; p.Cio = A; p.sCio = 262144; p.ldc = 512;
        p.gdiag = gdiag; p.anacc = AnAcc; p.abf = Abf; p.K = 128;
        gemm_body(p, z);
    } else if (z < 16) {
        p.alay = 3; p.Ap = Vnt; p.lda = 512; p.sA = 1048576;
        p.blay = 1; p.Bp = Alpha; p.ldb = 128; p.sB = 65536;
        p.epi = 2; p.Cio = S; p.sbf = Sbf; p.sCio = 262144; p.ldc = 512; p.K = 128;
        gemm_body(p, z - 8);
    } else {
        if (blockIdx.x >= 2) return;
        p.alay = 4; p.Ap = P; p.lda = 128; p.sA = 16384;
        p.blay = 2; p.Bp = Vnt; p.ldb = 512; p.sB = 1048576;
        p.epi = 3; p.Cp = Obt; p.ldc = 512; p.sC = 1048576;
        p.Cio = (float*)OBSA; p.sCio = 131072; p.K = 128;
        gemm_body(p, z - 16);
    }
}

// ---------------- symmetric LDL^T elimination + level-doubling triangular inverse ----------------
__global__ __launch_bounds__(512)
void elim_kernel(const float* __restrict__ G, float* __restrict__ Tg,
                 const float* __restrict__ sseq, float* __restrict__ invd,
                 float* __restrict__ ca, float* __restrict__ cb,
                 float* __restrict__ dsum_g, const int t0)
{
    const int b = blockIdx.x, tid = threadIdx.x, lane = tid & 63, wave = tid >> 6;
    __shared__ __align__(16) float E[128][132];
    __shared__ __align__(16) float Cs[128][132];
    __shared__ __align__(16) float Scr[2368];
    __shared__ float del[128];
    float (*Tm)[132] = E;
    float (*LpT)[132] = (float(*)[132])Scr;
    float (*SpT)[132] = (float(*)[132])(Scr + 1056);

    {
        const float4* Gb = (const float4*)(G + (size_t)b * 16384);
        for (int idx = tid; idx < 4096; idx += ETH) {
            const int r = idx >> 5, c4 = idx & 31;
            ((float4*)&E[r][0])[c4] = Gb[idx];
        }
    }
    if (tid < 128) dsum_g[b * 128 + tid] = 0.f;
    __syncthreads();

    for (int p = 0; p < 16; ++p) {
        const int pc0 = p * 8;
        if (wave == 0) {
            float pr0[8], pr1[8];
            #pragma unroll
            for (int j = 0; j < 8; ++j) {
                pr0[j] = E[pc0 + j][lane];
                pr1[j] = E[pc0 + j][64 + lane];
            }
            float dl[8];
            const bool hi = (pc0 >= 64);
            #pragma unroll
            for (int j = 0; j < 8; ++j) {
                const int t = pc0 + j;
                const int pl = t & 63;
                float prow[8];
                #pragma unroll
                for (int c = 0; c < 8; ++c) {
                    const float v0 = __shfl(pr0[c], pl);
                    const float v1 = __shfl(pr1[c], pl);
                    prow[c] = hi ? v1 : v0;
                }
                const float d = fmaxf(1.f + prow[j], 1e-6f);
                dl[j] = d;
                const float inv = 1.f / d;
                if (lane > t) {
                    const float coef = pr0[j] * inv;
                    #pragma unroll
                    for (int c = j + 1; c < 8; ++c) pr0[c] = fmaf(-coef, prow[c], pr0[c]);
                }
                if (lane + 64 > t) {
                    const float coef = pr1[j] * inv;
                    #pragma unroll
                    for (int c = j + 1; c < 8; ++c) pr1[c] = fmaf(-coef, prow[c], pr1[c]);
                }
            }
            #pragma unroll
            for (int j = 0; j < 8; ++j) {
                const float idj = 1.f / dl[j];
                const int t = pc0 + j;
                {
                    const bool below = (lane > t);
                    const float y = below ? pr0[j] : 0.f;
                    const float l = y * idj;
                    LpT[j][lane] = l; SpT[j][lane] = y; Cs[t][lane] = l;
                }
                {
                    const int r = lane + 64;
                    const bool below = (r > t);
                    const float y = below ? pr1[j] : 0.f;
                    const float l = y * idj;
                    LpT[j][r] = l; SpT[j][r] = y; Cs[t][r] = l;
                }
            }
            if (lane < 8) del[pc0 + lane] = dl[lane];
        }
        __syncthreads();
        const int r0b = pc0 + 8;
        if (r0b < 128) {
            const int nrows = 128 - r0b;
            const int c40 = r0b >> 2, nc4 = 32 - c40;
            for (int idx = tid; idx < nrows * nc4; idx += ETH) {
                const int rr = idx / nc4, cc = idx - rr * nc4;
                const int r = r0b + rr, c4 = c40 + cc;
                float4 e = ((float4*)&E[r][0])[c4];
                #pragma unroll
                for (int j = 0; j < 8; ++j) {
                    const float lv = LpT[j][r];
                    const float4 sv = ((const float4*)&SpT[j][0])[c4];
                    e.x = fmaf(-lv, sv.x, e.x);
                    e.y = fmaf(-lv, sv.y, e.y);
                    e.z = fmaf(-lv, sv.z, e.z);
                    e.w = fmaf(-lv, sv.w, e.w);
                }
                ((float4*)&E[r][0])[c4] = e;
            }
        }
        __syncthreads();
    }

    // ---- inversion: Tm = (I+C)^-1 (Tm aliases E; Scr reused as matmul scratch) ----
    for (int idx = tid; idx < 4224; idx += ETH)
        ((float4*)&Tm[0][0])[idx] = make_float4(0.f, 0.f, 0.f, 0.f);
    __syncthreads();
    if (tid < 128) Tm[tid][tid] = 1.f;
    __syncthreads();
    {
        const int g = tid >> 3, c = tid & 7;
        if (g < 16) {
            for (int r2 = c - 1; r2 >= 0; --r2) {
                float s = 0.f;
                for (int kk = r2 + 1; kk <= c; ++kk)
                    s = fmaf(Cs[8 * g + r2][8 * g + kk],
                             (kk == c) ? 1.f : Tm[8 * g + kk][8 * g + c], s);
                Tm[8 * g + r2][8 * g + c] = -s;
            }
        }
    }
    __syncthreads();
    for (int s = 8; s <= 64; s <<= 1) {
        const int npairs = 64 / s;
        const int nj = (s == 64) ? 32 : s;
        const int stride = nj + 4;
        const int nj4 = nj >> 2;
        const int Nel = npairs * s * nj4;
        const int nhalf = (s == 64) ? 2 : 1;
        for (int jh = 0; jh < nhalf; ++jh) {
            for (int idx = tid; idx < Nel; idx += ETH) {
                const int p2 = idx / (s * nj4), rem = idx - p2 * s * nj4;
                const int i = rem / nj4, j4 = rem - i * nj4;
                const int I0 = 2 * s * p2, J0 = I0 + s;
                const int jc = j4 * 4 + jh * 32;
                float4 x = make_float4(0.f, 0.f, 0.f, 0.f);
                for (int k = 0; k < s; ++k) {
                    const float cv = Cs[I0 + i][J0 + k];
                    const float4 tv = *(const float4*)&Tm[J0 + k][J0 + jc];
                    x.x = fmaf(cv, tv.x, x.x);
                    x.y = fmaf(cv, tv.y, x.y);
                    x.z = fmaf(cv, tv.z, x.z);
                    x.w = fmaf(cv, tv.w, x.w);
                }
                *(float4*)&Scr[p2 * s * stride + i * stride + j4 * 4] = x;
            }
            __syncthreads();
            for (int idx = tid; idx < Nel; idx += ETH) {
                const int p2 = idx / (s * nj4), rem = idx - p2 * s * nj4;
                const int i = rem / nj4, j4 = rem - i * nj4;
                const int I0 = 2 * s * p2, J0 = I0 + s;
                const int jc = j4 * 4 + jh * 32;
                float4 y = make_float4(0.f, 0.f, 0.f, 0.f);
                for (int k = 0; k < s; ++k) {
                    const float tv = Tm[I0 + i][I0 + k];
                    const float4 xv = *(const float4*)&Scr[p2 * s * stride + k * stride + j4 * 4];
                    y.x = fmaf(tv, xv.x, y.x);
                    y.y = fmaf(tv, xv.y, y.y);
                    y.z = fmaf(tv, xv.z, y.z);
                    y.w = fmaf(tv, xv.w, y.w);
                }
                float4 o;
                o.x = -y.x; o.y = -y.y; o.z = -y.z; o.w = -y.w;
                *(float4*)&Tm[I0 + i][J0 + jc] = o;
            }
            __syncthreads();
        }
    }
    {
        float4* Tgb = (float4*)(Tg + (size_t)b * 16384);
        for (int idx = tid; idx < 4096; idx += ETH) {
            const int r = idx >> 5, c4 = idx & 31;
            Tgb[idx] = ((const float4*)&Tm[r][0])[c4];
        }
    }
    if (tid < 128) {
        const float d = del[tid];
        const float s = sseq[(size_t)b * TT + t0 + tid];
        invd[b * 128 + tid] = 1.f / d;
        ca[b * 128 + tid] = s / d;
        cb[b * 128 + tid] = (tid == 127) ? s * 1e-6f : 0.f;
    }
}

// ---------------- guard ----------------
__global__ __launch_bounds__(256)
void guard_kernel(const float* __restrict__ dsum_g, const float* __restrict__ Ga,
                  const float* __restrict__ Gv, float* __restrict__ SnSq,
                  float* __restrict__ AnAcc, float* __restrict__ gdiag)
{
    const int b = blockIdx.x, tid = threadIdx.x;
    __shared__ float rpart[256], dsh[128], mdia[128];
    const int t = tid & 127, half = tid >> 7;
    const float* gv = Gv + (size_t)b * 16384 + t * 128;
    const float* ga = Ga + (size_t)b * 16384 + t * 128;
    float rs = 0.f;
    for (int j = half; j < t; j += 2) rs = fmaf(gv[j], ga[j], rs);
    rpart[tid] = rs;
    if (half == 0) { dsh[t] = dsum_g[b * 128 + t]; mdia[t] = gv[t] * ga[t]; }
    __syncthreads();
    if (tid == 0) {
        const float An2 = AnAcc[b];
        float Sn2 = SnSq[b], D = 0.f, T = 0.f;
        int ng = 0;
        for (int t2 = 0; t2 < 128; ++t2) {
            D += dsh[t2];
            T += mdia[t2] + 2.f * (rpart[t2] + rpart[t2 + 128]);
            const float sn2 = Sn2 + 2.f * D + T;
            if (sn2 > 1e6f || An2 > 1e6f) ++ng;
        }
        SnSq[b] = Sn2 + 2.f * D + T;
        gdiag[b] = 1e-6f + (float)ng * 1e-5f;
        AnAcc[b] = 0.f;
    }
}

extern "C" void kernel_launch(void* const* d_in, const int* in_sizes, int n_in,
                              void* d_out, int out_size, void* d_ws, size_t ws_size,
                              hipStream_t stream)
{
    const float* x  = (const float*)d_in[0];
    const float* Wq = (const float*)d_in[1];
    const float* bq = (const float*)d_in[2];
    const float* Wk = (const float*)d_in[3];
    const float* bk = (const float*)d_in[4];
    const float* Wv = (const float*)d_in[5];
    const float* bv = (const float*)d_in[6];
    const float* Wo = (const float*)d_in[7];
    const float* bo = (const float*)d_in[8];

    char* ws = (char*)d_ws;
    u16* Qb    = (u16*)(ws);
    u16* Ub    = (u16*)(ws + (16ull << 20));
    u16* Vnb   = (u16*)(ws + (32ull << 20));
    u16* Ob    = (u16*)(ws + (48ull << 20));   // also x_bf before chunk loop
    u16* x_bf  = Ob;
    float* A    = (float*)(ws + (64ull << 20));
    float* S    = (float*)(ws + (72ull << 20));
    float* Wm   = (float*)(ws + (80ull << 20));
    float* Z    = (float*)(ws + (82ull << 20));
    float* Zs   = (float*)(ws + (84ull << 20));
    float* Alpha= (float*)(ws + (86ull << 20));
    float* OBSA = (float*)(ws + (88ull << 20));
    float* G    = (float*)(ws + (92ull << 20));
    float* Tg   = (float*)(ws + (92ull << 20) + (512ull << 10));
    float* P    = (float*)(ws + (93ull << 20));
    float* Ga   = (float*)(ws + (93ull << 20) + (512ull << 10));
    float* Gv   = (float*)(ws + (94ull << 20));
    float* invd = (float*)(ws + (94ull << 20) + (512ull << 10));
    float* ca   = (float*)(ws + (94ull << 20) + (516ull << 10));
    float* cb   = (float*)(ws + (94ull << 20) + (520ull << 10));
    float* sseq = (float*)(ws + (94ull << 20) + (528ull << 10));
    float* SnSq = (float*)(ws + (94ull << 20) + (600ull << 10));
    float* AnAcc= (float*)(ws + (94ull << 20) + (600ull << 10) + 64);
    float* gdiag= (float*)(ws + (94ull << 20) + (600ull << 10) + 128);
    float* dsum = (float*)(ws + (94ull << 20) + (604ull << 10));
    u16* Wq_bf = (u16*)(ws + (95ull << 20));
    u16* Wk_bf = (u16*)(ws + (95ull << 20) + (512ull << 10));
    u16* Wv_bf = (u16*)(ws + (96ull << 20));
    u16* Wo_bf = (u16*)(ws + (96ull << 20) + (512ull << 10));
    u16* S_bf  = (u16*)(ws + (97ull << 20));   // 4 MiB bf16 mirror of S
    u16* AlT   = (u16*)(ws + (101ull << 20));  // 1 MiB AlphaT bf16

    const bool big = (ws_size >= (111ull << 20));
    u16* A_bf = big ? (u16*)(ws + (102ull << 20)) : (u16*)nullptr;  // 8 MiB

    f2bf_kernel<<<2048, 256, 0, stream>>>((const float4*)x, (ushort4*)x_bf, 2097152);
    wconv_kernel<<<dim3(256, 4), 256, 0, stream>>>(
        (const float4*)Wq, (const float4*)Wk, (const float4*)Wv, (const float4*)Wo,
        (ushort4*)Wq_bf, (ushort4*)Wk_bf, (ushort4*)Wv_bf, (ushort4*)Wo_bf);

    mfma_gemm<1><<<dim3(128, 4), 256, 0, stream>>>(x_bf, Wq_bf, bq, Qb, 1.f);
    mfma_gemm<1><<<dim3(128, 4), 256, 0, stream>>>(x_bf, Wk_bf, bk, Ub, 0.04419417382415922f);
    mfma_gemm<1><<<dim3(128, 4), 256, 0, stream>>>(x_bf, Wv_bf, bv, Vnb, 1.f);
    prep_kernel<<<4096, 256, 0, stream>>>(Qb, Ub, Vnb, sseq);
    init_kernel<<<2048, 256, 0, stream>>>((float4*)A, (float4*)S, (ushort4*)S_bf,
                                          (ushort4*)A_bf, SnSq, AnAcc);

    for (int c = 0; c < NC; ++c) {
        const int t0 = c * LL;
        const u16* Ut = Ub + (size_t)t0 * 512;
        const u16* Qt = Qb + (size_t)t0 * 512;
        const u16* Vt = Vnb + (size_t)t0 * 512;
        // K1: W = A x U^T (MFMA via A_bf when workspace allows, vector fallback)
        if (big) {
            mfk1_kernel<<<dim3(4, 1, 8), 256, 0, stream>>>(A_bf, Ut, Wm);
        } else {
            GP p1{}; p1.alay = 0; p1.Ap = A; p1.lda = 512; p1.sA = 262144;
            p1.blay = 3; p1.Bp = Ut; p1.ldb = 512; p1.sB = 1048576;
            p1.epi = 0; p1.Cp = Wm; p1.ldc = 128; p1.sC = 65536; p1.K = 512;
            gemmx<<<dim3(8, 2, 8), 256, 0, stream>>>(p1);
        }
        // K2: G = U^T W
        GP p2{}; p2.alay = 2; p2.Ap = Ut; p2.lda = 512; p2.sA = 1048576;
        p2.blay = 0; p2.Bp = Wm; p2.ldb = 128; p2.sB = 65536;
        p2.epi = 0; p2.Cp = G; p2.ldc = 128; p2.sC = 16384; p2.K = 512;
        gemmx<<<dim3(2, 2, 8), 256, 0, stream>>>(p2);
        elim_kernel<<<8, 512, 0, stream>>>(G, Tg, sseq, invd, ca, cb, dsum, t0);
        // p4: Z/Zs/Alpha (f32) + AlphaT (bf16) = W x T with scale epilogue
        GP p4{}; p4.alay = 0; p4.Ap = Wm; p4.lda = 128; p4.sA = 65536;
        p4.blay = 0; p4.Bp = Tg; p4.ldb = 128; p4.sB = 16384;
        p4.epi = 4; p4.Cp = Z; p4.Zsp = Zs; p4.Alphap = Alpha; p4.albt = AlT;
        p4.invdp = invd; p4.cap = ca; p4.cbp = cb;
        p4.Ulastp = Ub + (size_t)(t0 + 127) * 512;
        p4.K = 128; p4.ldc = 128; p4.sC = 65536;
        gemmx<<<dim3(8, 2, 8), 256, 0, stream>>>(p4);
        // lvl5: MFMA K6 (OBSA + dsum) + MFMA gram3 (P, Ga, Gv)
        lvl5_kernel<<<dim3(4, 2, 32), 256, 0, stream>>>(S_bf, AlT, Alpha, Qt, Vt,
            P, Ga, Gv, OBSA, dsum);
        guard_kernel<<<8, 256, 0, stream>>>(dsum, Ga, Gv, SnSq, AnAcc, gdiag);
        // lvl7: K10 (A update + A_bf mirror) + K9 (S update + S_bf mirror) + K8 (O out)
        lvl7_kernel<<<dim3(8, 8, 24), 256, 0, stream>>>(P, Vt, Ob + (size_t)t0 * 512, OBSA,
            Alpha, Zs, Z, S, S_bf, A, A_bf, gdiag, AnAcc);
    }
    mfma_gemm<0><<<dim3(128, 4), 256, 0, stream>>>(Ob, Wo_bf, bo, d_out, 1.f);
}

// Round 16
// 2966.714 us; speedup vs baseline: 1.4220x; 1.0467x over previous
//
#include <hip/hip_runtime.h>
#include <hip/hip_bf16.h>

#define BB 8
#define TT 2048
#define DD 512
#define LL 128
#define NC 16
#define ETH 512

typedef unsigned short u16;
typedef unsigned int u32;
typedef __attribute__((ext_vector_type(8))) short bf16x8v;
typedef __attribute__((ext_vector_type(4))) float f32x4v;

__device__ __forceinline__ float bf2f(u32 h) { return __uint_as_float(h << 16); }
__device__ __forceinline__ u16 f2bf(float f) {
    u32 u = __float_as_uint(f);
    u += 0x7fffu + ((u >> 16) & 1u);
    return (u16)(u >> 16);
}
__device__ __forceinline__ float wred64(float v) {
    #pragma unroll
    for (int off = 32; off; off >>= 1) v += __shfl_xor(v, off);
    return v;
}
__device__ __forceinline__ void unpack8(uint4 r, float* f) {
    f[0] = bf2f(r.x & 0xffff); f[1] = bf2f(r.x >> 16);
    f[2] = bf2f(r.y & 0xffff); f[3] = bf2f(r.y >> 16);
    f[4] = bf2f(r.z & 0xffff); f[5] = bf2f(r.z >> 16);
    f[6] = bf2f(r.w & 0xffff); f[7] = bf2f(r.w >> 16);
}

// ---------------- f32 -> bf16 convert ----------------
__global__ __launch_bounds__(256)
void f2bf_kernel(const float4* __restrict__ in, ushort4* __restrict__ out, const int n4)
{
    int i = blockIdx.x * 256 + threadIdx.x;
    const int stride = gridDim.x * 256;
    for (; i < n4; i += stride) {
        const float4 v = in[i];
        ushort4 o;
        o.x = f2bf(v.x); o.y = f2bf(v.y); o.z = f2bf(v.z); o.w = f2bf(v.w);
        out[i] = o;
    }
}

__global__ __launch_bounds__(256)
void wconv_kernel(const float4* __restrict__ Wq, const float4* __restrict__ Wk,
                  const float4* __restrict__ Wv, const float4* __restrict__ Wo,
                  ushort4* __restrict__ oq, ushort4* __restrict__ ok,
                  ushort4* __restrict__ ov, ushort4* __restrict__ oo)
{
    const int i = blockIdx.x * 256 + threadIdx.x;
    const int y = blockIdx.y;
    const float4* src = (y == 0) ? Wq : (y == 1) ? Wk : (y == 2) ? Wv : Wo;
    ushort4* dst = (y == 0) ? oq : (y == 1) ? ok : (y == 2) ? ov : oo;
    const float4 v = src[i];
    ushort4 o;
    o.x = f2bf(v.x); o.y = f2bf(v.y); o.z = f2bf(v.z); o.w = f2bf(v.w);
    dst[i] = o;
}

// ---------------- MFMA bf16 GEMM for projections (round-5 proven) ----------------
template<int OUT_BF>
__global__ __launch_bounds__(256)
void mfma_gemm(const u16* __restrict__ Abf, const u16* __restrict__ Bbf,
               const float* __restrict__ bias, void* __restrict__ Cout,
               const float outscale)
{
    __shared__ u16 Asm[128 * 64];
    __shared__ u16 Bsm[128 * 64];
    const int tid = threadIdx.x;
    const int wave = tid >> 6, lane = tid & 63;
    const int wm = wave >> 1, wn = wave & 1;
    const int m0 = blockIdx.x * 128, n0 = blockIdx.y * 128;

    f32x4v acc[4][4];
    #pragma unroll
    for (int i = 0; i < 4; ++i)
        #pragma unroll
        for (int j = 0; j < 4; ++j)
            acc[i][j] = (f32x4v){0.f, 0.f, 0.f, 0.f};

    const u16* gsrcA[4];
    const u16* gsrcB[4];
    #pragma unroll
    for (int i = 0; i < 4; ++i) {
        const int idx = i * 256 + tid;
        const int row = idx >> 3, c = idx & 7;
        const int kb = c ^ (row & 7);
        gsrcA[i] = Abf + (size_t)(m0 + row) * 512 + kb * 8;
        gsrcB[i] = Bbf + (size_t)(n0 + row) * 512 + kb * 8;
    }

    for (int k0 = 0; k0 < 512; k0 += 64) {
        __syncthreads();
        #pragma unroll
        for (int i = 0; i < 4; ++i) {
            __builtin_amdgcn_global_load_lds(
                (__attribute__((address_space(1))) void*)(gsrcA[i] + k0),
                (__attribute__((address_space(3))) void*)(Asm + (size_t)(i * 256 + wave * 64) * 8),
                16, 0, 0);
            __builtin_amdgcn_global_load_lds(
                (__attribute__((address_space(1))) void*)(gsrcB[i] + k0),
                (__attribute__((address_space(3))) void*)(Bsm + (size_t)(i * 256 + wave * 64) * 8),
                16, 0, 0);
        }
        asm volatile("s_waitcnt vmcnt(0)" ::: "memory");
        __syncthreads();

        const int l15 = lane & 15, lhi = lane >> 4;
        bf16x8v af[4][2], bfr[4][2];
        #pragma unroll
        for (int mf = 0; mf < 4; ++mf) {
            const int row = wm * 64 + mf * 16 + l15;
            const int sw = (row & 7) << 4;
            #pragma unroll
            for (int ks = 0; ks < 2; ++ks) {
                const int kbyte = ks * 64 + lhi * 16;
                af[mf][ks] = *(const bf16x8v*)((const char*)Asm + row * 128 + (kbyte ^ sw));
            }
        }
        #pragma unroll
        for (int nf = 0; nf < 4; ++nf) {
            const int row = wn * 64 + nf * 16 + l15;
            const int sw = (row & 7) << 4;
            #pragma unroll
            for (int ks = 0; ks < 2; ++ks) {
                const int kbyte = ks * 64 + lhi * 16;
                bfr[nf][ks] = *(const bf16x8v*)((const char*)Bsm + row * 128 + (kbyte ^ sw));
            }
        }
        #pragma unroll
        for (int ks = 0; ks < 2; ++ks)
            #pragma unroll
            for (int mf = 0; mf < 4; ++mf)
                #pragma unroll
                for (int nf = 0; nf < 4; ++nf)
                    acc[mf][nf] = __builtin_amdgcn_mfma_f32_16x16x32_bf16(
                        af[mf][ks], bfr[nf][ks], acc[mf][nf], 0, 0, 0);
    }
    const int l15 = lane & 15, lhi = lane >> 4;
    #pragma unroll
    for (int mf = 0; mf < 4; ++mf) {
        #pragma unroll
        for (int nf = 0; nf < 4; ++nf) {
            const int n = n0 + wn * 64 + nf * 16 + l15;
            const float bsv = bias[n];
            #pragma unroll
            for (int r = 0; r < 4; ++r) {
                const int m = m0 + wm * 64 + mf * 16 + lhi * 4 + r;
                const float val = (acc[mf][nf][r] + bsv) * outscale;
                if (OUT_BF) ((u16*)Cout)[(size_t)m * 512 + n] = f2bf(val);
                else        ((float*)Cout)[(size_t)m * 512 + n] = val;
            }
        }
    }
}

// ---------------- MFMA K6 body (256 thr, 4 waves): OBSA = S_bf x [Q | AlphaT] ----------------
__device__ __forceinline__ void mfk6_body(const u16* __restrict__ Sb,
    const u16* __restrict__ Qt, const u16* __restrict__ AlT,
    const u16* __restrict__ Vnt, float* __restrict__ OBSA,
    float* __restrict__ dsum, const int bz)
{
    __shared__ u16 Ah[128 * 64];
    __shared__ u16 Bh[128 * 64];
    const int tid = threadIdx.x, wave = tid >> 6, lane = tid & 63;
    const int wm = wave >> 1, wn = wave & 1;
    const int m0 = blockIdx.x * 128, n0 = blockIdx.y * 128;

    f32x4v acc[4][4];
    #pragma unroll
    for (int i = 0; i < 4; ++i)
        #pragma unroll
        for (int j = 0; j < 4; ++j)
            acc[i][j] = (f32x4v){0.f, 0.f, 0.f, 0.f};

    const u16* Abase = Sb + (size_t)bz * 262144;
    const u16* Bbase = (n0 == 0) ? (Qt + (size_t)bz * 1048576)
                                 : (AlT + (size_t)bz * 65536);
    const u16* gA[4]; const u16* gB[4];
    #pragma unroll
    for (int i = 0; i < 4; ++i) {
        const int idx = i * 256 + tid, row = idx >> 3, c = idx & 7;
        const int kb = c ^ (row & 7);
        gA[i] = Abase + (size_t)(m0 + row) * 512 + kb * 8;
        gB[i] = Bbase + (size_t)row * 512 + kb * 8;
    }
    for (int k0 = 0; k0 < 512; k0 += 64) {
        __syncthreads();
        #pragma unroll
        for (int i = 0; i < 4; ++i) {
            const int dst = (i * 256 + wave * 64) * 8;
            __builtin_amdgcn_global_load_lds(
                (__attribute__((address_space(1))) void*)(gA[i] + k0),
                (__attribute__((address_space(3))) void*)(Ah + dst), 16, 0, 0);
            __builtin_amdgcn_global_load_lds(
                (__attribute__((address_space(1))) void*)(gB[i] + k0),
                (__attribute__((address_space(3))) void*)(Bh + dst), 16, 0, 0);
        }
        asm volatile("s_waitcnt vmcnt(0)" ::: "memory");
        __syncthreads();

        const int l15 = lane & 15, lhi = lane >> 4;
        bf16x8v af[4][2], bfr[4][2];
        #pragma unroll
        for (int mf = 0; mf < 4; ++mf) {
            const int row = wm * 64 + mf * 16 + l15, sw = (row & 7) << 4;
            #pragma unroll
            for (int ks = 0; ks < 2; ++ks) {
                const int kb2 = (ks * 64 + lhi * 16) ^ sw;
                af[mf][ks] = *(const bf16x8v*)((const char*)Ah + row * 128 + kb2);
            }
        }
        #pragma unroll
        for (int nf = 0; nf < 4; ++nf) {
            const int row = wn * 64 + nf * 16 + l15, sw = (row & 7) << 4;
            #pragma unroll
            for (int ks = 0; ks < 2; ++ks) {
                const int kb2 = (ks * 64 + lhi * 16) ^ sw;
                bfr[nf][ks] = *(const bf16x8v*)((const char*)Bh + row * 128 + kb2);
            }
        }
        #pragma unroll
        for (int ks = 0; ks < 2; ++ks)
            #pragma unroll
            for (int mf = 0; mf < 4; ++mf)
                #pragma unroll
                for (int nf = 0; nf < 4; ++nf)
                    acc[mf][nf] = __builtin_amdgcn_mfma_f32_16x16x32_bf16(
                        af[mf][ks], bfr[nf][ks], acc[mf][nf], 0, 0, 0);
    }
    const int l15 = lane & 15, lhi = lane >> 4;
    float* C = OBSA + (size_t)bz * 131072;
    #pragma unroll
    for (int mf = 0; mf < 4; ++mf)
        #pragma unroll
        for (int nf = 0; nf < 4; ++nf) {
            const int n = n0 + wn * 64 + nf * 16 + l15;
            #pragma unroll
            for (int r = 0; r < 4; ++r) {
                const int m = m0 + wm * 64 + mf * 16 + lhi * 4 + r;
                C[(size_t)m * 256 + n] = acc[mf][nf][r];
            }
        }
    if (n0 == 128) {
        const u16* Vn = Vnt + (size_t)bz * 1048576;
        #pragma unroll
        for (int nf = 0; nf < 4; ++nf) {
            const int n = n0 + wn * 64 + nf * 16 + l15;
            const int i2 = n - 128;
            float part = 0.f;
            #pragma unroll
            for (int mf = 0; mf < 4; ++mf) {
                const int m = m0 + wm * 64 + mf * 16 + lhi * 4;
                const ushort4 vr = *(const ushort4*)(Vn + (size_t)i2 * 512 + m);
                part += bf2f(vr.x) * acc[mf][nf][0] + bf2f(vr.y) * acc[mf][nf][1]
                      + bf2f(vr.z) * acc[mf][nf][2] + bf2f(vr.w) * acc[mf][nf][3];
            }
            part += __shfl_xor(part, 16);
            part += __shfl_xor(part, 32);
            if (lhi == 0) atomicAdd(dsum + bz * 128 + i2, part);
        }
    }
}

// ---------------- MFMA gram body (256 thr): C[128][128] = Arows x Brows^T, K=512 bf16 ----------------
__device__ __forceinline__ void mfg_body(const u16* __restrict__ Ab,
    const u16* __restrict__ Bb, float* __restrict__ Cq)
{
    __shared__ u16 Agh[128 * 64];
    __shared__ u16 Bgh[128 * 64];
    const int tid = threadIdx.x, wave = tid >> 6, lane = tid & 63;
    const int wm = wave >> 1, wn = wave & 1;

    f32x4v acc[4][4];
    #pragma unroll
    for (int i = 0; i < 4; ++i)
        #pragma unroll
        for (int j = 0; j < 4; ++j)
            acc[i][j] = (f32x4v){0.f, 0.f, 0.f, 0.f};

    const u16* gA[4]; const u16* gB[4];
    #pragma unroll
    for (int i = 0; i < 4; ++i) {
        const int idx = i * 256 + tid, row = idx >> 3, c = idx & 7;
        const int kb = c ^ (row & 7);
        gA[i] = Ab + (size_t)row * 512 + kb * 8;
        gB[i] = Bb + (size_t)row * 512 + kb * 8;
    }
    for (int k0 = 0; k0 < 512; k0 += 64) {
        __syncthreads();
        #pragma unroll
        for (int i = 0; i < 4; ++i) {
            const int dst = (i * 256 + wave * 64) * 8;
            __builtin_amdgcn_global_load_lds(
                (__attribute__((address_space(1))) void*)(gA[i] + k0),
                (__attribute__((address_space(3))) void*)(Agh + dst), 16, 0, 0);
            __builtin_amdgcn_global_load_lds(
                (__attribute__((address_space(1))) void*)(gB[i] + k0),
                (__attribute__((address_space(3))) void*)(Bgh + dst), 16, 0, 0);
        }
        asm volatile("s_waitcnt vmcnt(0)" ::: "memory");
        __syncthreads();

        const int l15 = lane & 15, lhi = lane >> 4;
        bf16x8v af[4][2], bfr[4][2];
        #pragma unroll
        for (int mf = 0; mf < 4; ++mf) {
            const int row = wm * 64 + mf * 16 + l15, sw = (row & 7) << 4;
            #pragma unroll
            for (int ks = 0; ks < 2; ++ks) {
                const int kb2 = (ks * 64 + lhi * 16) ^ sw;
                af[mf][ks] = *(const bf16x8v*)((const char*)Agh + row * 128 + kb2);
            }
        }
        #pragma unroll
        for (int nf = 0; nf < 4; ++nf) {
            const int row = wn * 64 + nf * 16 + l15, sw = (row & 7) << 4;
            #pragma unroll
            for (int ks = 0; ks < 2; ++ks) {
                const int kb2 = (ks * 64 + lhi * 16) ^ sw;
                bfr[nf][ks] = *(const bf16x8v*)((const char*)Bgh + row * 128 + kb2);
            }
        }
        #pragma unroll
        for (int ks = 0; ks < 2; ++ks)
            #pragma unroll
            for (int mf = 0; mf < 4; ++mf)
                #pragma unroll
                for (int nf = 0; nf < 4; ++nf)
                    acc[mf][nf] = __builtin_amdgcn_mfma_f32_16x16x32_bf16(
                        af[mf][ks], bfr[nf][ks], acc[mf][nf], 0, 0, 0);
    }
    const int l15 = lane & 15, lhi = lane >> 4;
    #pragma unroll
    for (int mf = 0; mf < 4; ++mf)
        #pragma unroll
        for (int nf = 0; nf < 4; ++nf) {
            const int n = wn * 64 + nf * 16 + l15;
            #pragma unroll
            for (int r = 0; r < 4; ++r) {
                const int m = wm * 64 + mf * 16 + lhi * 4 + r;
                Cq[(size_t)m * 128 + n] = acc[mf][nf][r];
            }
        }
}

// ---------------- MFMA K1: W = A_bf x U^T (M=512, N=128, K=512) ----------------
__global__ __launch_bounds__(256)
void mfk1_kernel(const u16* __restrict__ Abf, const u16* __restrict__ Ut,
                 float* __restrict__ Wm)
{
    __shared__ u16 Ah[128 * 64];
    __shared__ u16 Bh[128 * 64];
    const int tid = threadIdx.x, wave = tid >> 6, lane = tid & 63;
    const int wm = wave >> 1, wn = wave & 1;
    const int m0 = blockIdx.x * 128;
    const int bz = blockIdx.z;

    f32x4v acc[4][4];
    #pragma unroll
    for (int i = 0; i < 4; ++i)
        #pragma unroll
        for (int j = 0; j < 4; ++j)
            acc[i][j] = (f32x4v){0.f, 0.f, 0.f, 0.f};

    const u16* Abase = Abf + (size_t)bz * 262144;
    const u16* Bbase = Ut + (size_t)bz * 1048576;
    const u16* gA[4]; const u16* gB[4];
    #pragma unroll
    for (int i = 0; i < 4; ++i) {
        const int idx = i * 256 + tid, row = idx >> 3, c = idx & 7;
        const int kb = c ^ (row & 7);
        gA[i] = Abase + (size_t)(m0 + row) * 512 + kb * 8;
        gB[i] = Bbase + (size_t)row * 512 + kb * 8;
    }
    for (int k0 = 0; k0 < 512; k0 += 64) {
        __syncthreads();
        #pragma unroll
        for (int i = 0; i < 4; ++i) {
            const int dst = (i * 256 + wave * 64) * 8;
            __builtin_amdgcn_global_load_lds(
                (__attribute__((address_space(1))) void*)(gA[i] + k0),
                (__attribute__((address_space(3))) void*)(Ah + dst), 16, 0, 0);
            __builtin_amdgcn_global_load_lds(
                (__attribute__((address_space(1))) void*)(gB[i] + k0),
                (__attribute__((address_space(3))) void*)(Bh + dst), 16, 0, 0);
        }
        asm volatile("s_waitcnt vmcnt(0)" ::: "memory");
        __syncthreads();

        const int l15 = lane & 15, lhi = lane >> 4;
        bf16x8v af[4][2], bfr[4][2];
        #pragma unroll
        for (int mf = 0; mf < 4; ++mf) {
            const int row = wm * 64 + mf * 16 + l15, sw = (row & 7) << 4;
            #pragma unroll
            for (int ks = 0; ks < 2; ++ks) {
                const int kb2 = (ks * 64 + lhi * 16) ^ sw;
                af[mf][ks] = *(const bf16x8v*)((const char*)Ah + row * 128 + kb2);
            }
        }
        #pragma unroll
        for (int nf = 0; nf < 4; ++nf) {
            const int row = wn * 64 + nf * 16 + l15, sw = (row & 7) << 4;
            #pragma unroll
            for (int ks = 0; ks < 2; ++ks) {
                const int kb2 = (ks * 64 + lhi * 16) ^ sw;
                bfr[nf][ks] = *(const bf16x8v*)((const char*)Bh + row * 128 + kb2);
            }
        }
        #pragma unroll
        for (int ks = 0; ks < 2; ++ks)
            #pragma unroll
            for (int mf = 0; mf < 4; ++mf)
                #pragma unroll
                for (int nf = 0; nf < 4; ++nf)
                    acc[mf][nf] = __builtin_amdgcn_mfma_f32_16x16x32_bf16(
                        af[mf][ks], bfr[nf][ks], acc[mf][nf], 0, 0, 0);
    }
    const int l15 = lane & 15, lhi = lane >> 4;
    float* C = Wm + (size_t)bz * 65536;
    #pragma unroll
    for (int mf = 0; mf < 4; ++mf)
        #pragma unroll
        for (int nf = 0; nf < 4; ++nf) {
            const int n = wn * 64 + nf * 16 + l15;
            #pragma unroll
            for (int r = 0; r < 4; ++r) {
                const int m = m0 + wm * 64 + mf * 16 + lhi * 4 + r;
                C[(size_t)m * 128 + n] = acc[mf][nf][r];
            }
        }
}

// ---------------- MFMA K10: A -= (Zs_hi+Zs_lo)x(Z_hi+Z_lo)^T + gdiag*I (split bf16) ----------------
__device__ __forceinline__ void mfk10_body(char* smemc,
    const u16* __restrict__ Zshi, const u16* __restrict__ Zslo,
    const u16* __restrict__ Zhi, const u16* __restrict__ Zlo,
    float* __restrict__ A, u16* __restrict__ Abf,
    const float* __restrict__ gdiag, float* __restrict__ AnAcc, const int bz)
{
    u16* Ah = (u16*)smemc;
    u16* Al = (u16*)(smemc + 16384);
    u16* Bh = (u16*)(smemc + 32768);
    u16* Bl = (u16*)(smemc + 49152);
    const int tid = threadIdx.x, wave = tid >> 6, lane = tid & 63;
    const int wm = wave >> 1, wn = wave & 1;
    const int m0 = blockIdx.x * 128, n0 = blockIdx.y * 128;

    f32x4v acc[4][4];
    #pragma unroll
    for (int i = 0; i < 4; ++i)
        #pragma unroll
        for (int j = 0; j < 4; ++j)
            acc[i][j] = (f32x4v){0.f, 0.f, 0.f, 0.f};

    const u16* Ahb = Zshi + (size_t)bz * 65536;
    const u16* Alb = Zslo + (size_t)bz * 65536;
    const u16* Bhb = Zhi + (size_t)bz * 65536;
    const u16* Blb = Zlo + (size_t)bz * 65536;
    const u16* gAh[4]; const u16* gAl[4]; const u16* gBh[4]; const u16* gBl[4];
    #pragma unroll
    for (int i = 0; i < 4; ++i) {
        const int idx = i * 256 + tid, row = idx >> 3, c = idx & 7;
        const int kb = c ^ (row & 7);
        gAh[i] = Ahb + (size_t)(m0 + row) * 128 + kb * 8;
        gAl[i] = Alb + (size_t)(m0 + row) * 128 + kb * 8;
        gBh[i] = Bhb + (size_t)(n0 + row) * 128 + kb * 8;
        gBl[i] = Blb + (size_t)(n0 + row) * 128 + kb * 8;
    }
    for (int k0 = 0; k0 < 128; k0 += 64) {
        __syncthreads();
        #pragma unroll
        for (int i = 0; i < 4; ++i) {
            const int dst = (i * 256 + wave * 64) * 8;
            __builtin_amdgcn_global_load_lds(
                (__attribute__((address_space(1))) void*)(gAh[i] + k0),
                (__attribute__((address_space(3))) void*)(Ah + dst), 16, 0, 0);
            __builtin_amdgcn_global_load_lds(
                (__attribute__((address_space(1))) void*)(gAl[i] + k0),
                (__attribute__((address_space(3))) void*)(Al + dst), 16, 0, 0);
            __builtin_amdgcn_global_load_lds(
                (__attribute__((address_space(1))) void*)(gBh[i] + k0),
                (__attribute__((address_space(3))) void*)(Bh + dst), 16, 0, 0);
            __builtin_amdgcn_global_load_lds(
                (__attribute__((address_space(1))) void*)(gBl[i] + k0),
                (__attribute__((address_space(3))) void*)(Bl + dst), 16, 0, 0);
        }
        asm volatile("s_waitcnt vmcnt(0)" ::: "memory");
        __syncthreads();

        const int l15 = lane & 15, lhi = lane >> 4;
        bf16x8v ah[4][2], al[4][2], bh[4][2], bl[4][2];
        #pragma unroll
        for (int mf = 0; mf < 4; ++mf) {
            const int row = wm * 64 + mf * 16 + l15, sw = (row & 7) << 4;
            #pragma unroll
            for (int ks = 0; ks < 2; ++ks) {
                const int kb2 = (ks * 64 + lhi * 16) ^ sw;
                ah[mf][ks] = *(const bf16x8v*)((const char*)Ah + row * 128 + kb2);
                al[mf][ks] = *(const bf16x8v*)((const char*)Al + row * 128 + kb2);
            }
        }
        #pragma unroll
        for (int nf = 0; nf < 4; ++nf) {
            const int row = wn * 64 + nf * 16 + l15, sw = (row & 7) << 4;
            #pragma unroll
            for (int ks = 0; ks < 2; ++ks) {
                const int kb2 = (ks * 64 + lhi * 16) ^ sw;
                bh[nf][ks] = *(const bf16x8v*)((const char*)Bh + row * 128 + kb2);
                bl[nf][ks] = *(const bf16x8v*)((const char*)Bl + row * 128 + kb2);
            }
        }
        #pragma unroll
        for (int ks = 0; ks < 2; ++ks)
            #pragma unroll
            for (int mf = 0; mf < 4; ++mf)
                #pragma unroll
                for (int nf = 0; nf < 4; ++nf) {
                    acc[mf][nf] = __builtin_amdgcn_mfma_f32_16x16x32_bf16(
                        ah[mf][ks], bh[nf][ks], acc[mf][nf], 0, 0, 0);
                    acc[mf][nf] = __builtin_amdgcn_mfma_f32_16x16x32_bf16(
                        al[mf][ks], bh[nf][ks], acc[mf][nf], 0, 0, 0);
                    acc[mf][nf] = __builtin_amdgcn_mfma_f32_16x16x32_bf16(
                        ah[mf][ks], bl[nf][ks], acc[mf][nf], 0, 0, 0);
                }
    }
    const int l15 = lane & 15, lhi = lane >> 4;
    float* Ab = A + (size_t)bz * 262144;
    u16* Abfb = Abf ? (Abf + (size_t)bz * 262144) : (u16*)nullptr;
    const float gd = gdiag[bz];
    float v2 = 0.f;
    #pragma unroll
    for (int mf = 0; mf < 4; ++mf)
        #pragma unroll
        for (int nf = 0; nf < 4; ++nf) {
            const int n = n0 + wn * 64 + nf * 16 + l15;
            #pragma unroll
            for (int r = 0; r < 4; ++r) {
                const int m = m0 + wm * 64 + mf * 16 + lhi * 4 + r;
                const size_t idx = (size_t)m * 512 + n;
                const float v = Ab[idx] - acc[mf][nf][r] + ((m == n) ? gd : 0.f);
                Ab[idx] = v;
                if (Abfb) Abfb[idx] = f2bf(v);
                v2 = fmaf(v, v, v2);
            }
        }
    v2 = wred64(v2);
    if (lane == 0) atomicAdd(AnAcc + bz, v2);
}

// ---------------- MFMA K9: S += VnT x Alphab^T (bf16) ----------------
__device__ __forceinline__ void mfk9_body(char* smemc,
    const u16* __restrict__ VnTc, const u16* __restrict__ Alphab,
    float* __restrict__ S, u16* __restrict__ Sbf, const int bz)
{
    u16* Ah = (u16*)smemc;
    u16* Bh = (u16*)(smemc + 16384);
    const int tid = threadIdx.x, wave = tid >> 6, lane = tid & 63;
    const int wm = wave >> 1, wn = wave & 1;
    const int m0 = blockIdx.x * 128, n0 = blockIdx.y * 128;

    f32x4v acc[4][4];
    #pragma unroll
    for (int i = 0; i < 4; ++i)
        #pragma unroll
        for (int j = 0; j < 4; ++j)
            acc[i][j] = (f32x4v){0.f, 0.f, 0.f, 0.f};

    const u16* Ab = VnTc + (size_t)bz * 65536;
    const u16* Bb = Alphab + (size_t)bz * 65536;
    const u16* gA[4]; const u16* gB[4];
    #pragma unroll
    for (int i = 0; i < 4; ++i) {
        const int idx = i * 256 + tid, row = idx >> 3, c = idx & 7;
        const int kb = c ^ (row & 7);
        gA[i] = Ab + (size_t)(m0 + row) * 128 + kb * 8;
        gB[i] = Bb + (size_t)(n0 + row) * 128 + kb * 8;
    }
    for (int k0 = 0; k0 < 128; k0 += 64) {
        __syncthreads();
        #pragma unroll
        for (int i = 0; i < 4; ++i) {
            const int dst = (i * 256 + wave * 64) * 8;
            __builtin_amdgcn_global_load_lds(
                (__attribute__((address_space(1))) void*)(gA[i] + k0),
                (__attribute__((address_space(3))) void*)(Ah + dst), 16, 0, 0);
            __builtin_amdgcn_global_load_lds(
                (__attribute__((address_space(1))) void*)(gB[i] + k0),
                (__attribute__((address_space(3))) void*)(Bh + dst), 16, 0, 0);
        }
        asm volatile("s_waitcnt vmcnt(0)" ::: "memory");
        __syncthreads();

        const int l15 = lane & 15, lhi = lane >> 4;
        bf16x8v af[4][2], bfr[4][2];
        #pragma unroll
        for (int mf = 0; mf < 4; ++mf) {
            const int row = wm * 64 + mf * 16 + l15, sw = (row & 7) << 4;
            #pragma unroll
            for (int ks = 0; ks < 2; ++ks) {
                const int kb2 = (ks * 64 + lhi * 16) ^ sw;
                af[mf][ks] = *(const bf16x8v*)((const char*)Ah + row * 128 + kb2);
            }
        }
        #pragma unroll
        for (int nf = 0; nf < 4; ++nf) {
            const int row = wn * 64 + nf * 16 + l15, sw = (row & 7) << 4;
            #pragma unroll
            for (int ks = 0; ks < 2; ++ks) {
                const int kb2 = (ks * 64 + lhi * 16) ^ sw;
                bfr[nf][ks] = *(const bf16x8v*)((const char*)Bh + row * 128 + kb2);
            }
        }
        #pragma unroll
        for (int ks = 0; ks < 2; ++ks)
            #pragma unroll
            for (int mf = 0; mf < 4; ++mf)
                #pragma unroll
                for (int nf = 0; nf < 4; ++nf)
                    acc[mf][nf] = __builtin_amdgcn_mfma_f32_16x16x32_bf16(
                        af[mf][ks], bfr[nf][ks], acc[mf][nf], 0, 0, 0);
    }
    const int l15 = lane & 15, lhi = lane >> 4;
    float* Sb = S + (size_t)bz * 262144;
    u16* Sbfb = Sbf + (size_t)bz * 262144;
    #pragma unroll
    for (int mf = 0; mf < 4; ++mf)
        #pragma unroll
        for (int nf = 0; nf < 4; ++nf) {
            const int n = n0 + wn * 64 + nf * 16 + l15;
            #pragma unroll
            for (int r = 0; r < 4; ++r) {
                const int m = m0 + wm * 64 + mf * 16 + lhi * 4 + r;
                const size_t idx = (size_t)m * 512 + n;
                const float v = Sb[idx] + acc[mf][nf][r];
                Sb[idx] = v;
                Sbfb[idx] = f2bf(v);
            }
        }
}

// ---------------- lvl7a: K10 (z<8) + K9 (z 8-15), shared 64KB smem ----------------
__global__ __launch_bounds__(256)
void lvl7a_kernel(const u16* Zshi, const u16* Zslo, const u16* Zhi, const u16* Zlo,
                  float* A, u16* Abf, const float* gdiag, float* AnAcc,
                  const u16* VnTc, const u16* Alphab, float* S, u16* Sbf)
{
    __shared__ __align__(16) char smem[65536];
    const int z = blockIdx.z;
    if (z < 8) {
        mfk10_body(smem, Zshi, Zslo, Zhi, Zlo, A, Abf, gdiag, AnAcc, z);
    } else {
        mfk9_body(smem, VnTc, Alphab, S, Sbf, z - 8);
    }
}

// ---------------- prep: s_seq, Vn normalize ----------------
__global__ __launch_bounds__(256)
void prep_kernel(const u16* __restrict__ Qb, const u16* __restrict__ Ub,
                 u16* __restrict__ Vb, float* __restrict__ sseq)
{
    const int lane = threadIdx.x & 63, wid = threadIdx.x >> 6;
    const int row = blockIdx.x * 4 + wid;
    const size_t base = (size_t)row * DD;
    const uint4 qr = *(const uint4*)(Qb + base + lane * 8);
    const uint4 ur = *(const uint4*)(Ub + base + lane * 8);
    const uint4 vr = *(const uint4*)(Vb + base + lane * 8);
    float q[8], u[8], v[8];
    unpack8(qr, q); unpack8(ur, u); unpack8(vr, v);
    float sd = 0.f, nv = 0.f;
    #pragma unroll
    for (int e = 0; e < 8; ++e) { sd = fmaf(q[e], u[e], sd); nv = fmaf(v[e], v[e], nv); }
    #pragma unroll
    for (int off = 32; off; off >>= 1) { sd += __shfl_xor(sd, off); nv += __shfl_xor(nv, off); }
    if (lane == 0) sseq[row] = sd * 22.627416997969522f;
    const float inv = 1.f / (sqrtf(nv) + 1e-6f);
    uint4 o;
    o.x = (u32)f2bf(v[0] * inv) | ((u32)f2bf(v[1] * inv) << 16);
    o.y = (u32)f2bf(v[2] * inv) | ((u32)f2bf(v[3] * inv) << 16);
    o.z = (u32)f2bf(v[4] * inv) | ((u32)f2bf(v[5] * inv) << 16);
    o.w = (u32)f2bf(v[6] * inv) | ((u32)f2bf(v[7] * inv) << 16);
    *(uint4*)(Vb + base + lane * 8) = o;
}

__global__ __launch_bounds__(256)
void init_kernel(float4* __restrict__ A4, float4* __restrict__ S4,
                 ushort4* __restrict__ Sbf4, ushort4* __restrict__ Abf4,
                 float* __restrict__ SnSq, float* __restrict__ AnAcc)
{
    const int gtid = blockIdx.x * 256 + threadIdx.x;
    const int N4 = BB * DD * DD / 4;
    const ushort4 z4 = {0, 0, 0, 0};
    for (int idx = gtid; idx < N4; idx += gridDim.x * 256) {
        const int e0 = idx << 2;
        const int r = (e0 >> 9) & 511;
        const int c = e0 & 511;
        float4 v;
        v.x = (c + 0 == r) ? 1.f : 0.f;
        v.y = (c + 1 == r) ? 1.f : 0.f;
        v.z = (c + 2 == r) ? 1.f : 0.f;
        v.w = (c + 3 == r) ? 1.f : 0.f;
        A4[idx] = v;
        S4[idx] = make_float4(0.f, 0.f, 0.f, 0.f);
        Sbf4[idx] = z4;
        if (Abf4) {
            ushort4 a;
            a.x = (c + 0 == r) ? 0x3F80 : 0;
            a.y = (c + 1 == r) ? 0x3F80 : 0;
            a.z = (c + 2 == r) ? 0x3F80 : 0;
            a.w = (c + 3 == r) ? 0x3F80 : 0;
            Abf4[idx] = a;
        }
    }
    if (gtid < BB) { SnSq[gtid] = 0.f; AnAcc[gtid] = 512.f; }
}

// ---------------- generic chunk GEMM ----------------
struct GP {
    int alay, blay, epi;
    const void* Ap; const void* Bp;
    void* Cp; float* Cio;
    const float* gdiag; float* anacc;
    const float* invdp; const float* cap; const float* cbp;
    const u16* Ulastp;
    u16 *zhi, *zlo, *zshi, *zslo, *alb, *albt;
    int lda, ldb, ldc, K;
    long sA, sB, sC, sCio;
};

__device__ __forceinline__ void gemm_body(const GP& p, const int bz) {
    __shared__ __align__(16) float As[32][68];
    __shared__ __align__(16) float Bs[32][68];
    const int m0 = blockIdx.x * 64, n0 = blockIdx.y * 64;
    const int tid = threadIdx.x, tx = tid & 15, ty = tid >> 4;
    float acc[4][4] = {};
    for (int k0 = 0; k0 < p.K; k0 += 32) {
        if (p.alay == 0) {
            const float* A = (const float*)p.Ap + (size_t)bz * p.sA;
            #pragma unroll
            for (int h = 0; h < 2; ++h) {
                const int g = tid + h * 256, m = g >> 3, k4 = (g & 7) * 4;
                const float4 r = *(const float4*)(A + (size_t)(m0 + m) * p.lda + k0 + k4);
                As[k4][m] = r.x; As[k4+1][m] = r.y; As[k4+2][m] = r.z; As[k4+3][m] = r.w;
            }
        } else if (p.alay == 2) {
            const u16* A = (const u16*)p.Ap + (size_t)bz * p.sA;
            #pragma unroll
            for (int h = 0; h < 2; ++h) {
                const int g = tid + h * 256, m = g >> 3, k4 = (g & 7) * 4;
                const ushort4 r = *(const ushort4*)(A + (size_t)(m0 + m) * p.lda + k0 + k4);
                As[k4][m]=bf2f(r.x); As[k4+1][m]=bf2f(r.y); As[k4+2][m]=bf2f(r.z); As[k4+3][m]=bf2f(r.w);
            }
        } else if (p.alay == 1 || p.alay == 4) {
            const float* A = (const float*)p.Ap + (size_t)bz * p.sA;
            #pragma unroll
            for (int h = 0; h < 2; ++h) {
                const int g = tid + h * 256, k = g >> 4, m4 = (g & 15) * 4;
                float4 r = *(const float4*)(A + (size_t)(k0 + k) * p.lda + m0 + m4);
                if (p.alay == 4) {
                    const int kg = k0 + k, mg = m0 + m4;
                    if (kg > mg + 0) r.x = 0.f;
                    if (kg > mg + 1) r.y = 0.f;
                    if (kg > mg + 2) r.z = 0.f;
                    if (kg > mg + 3) r.w = 0.f;
                }
                As[k][m4] = r.x; As[k][m4+1] = r.y; As[k][m4+2] = r.z; As[k][m4+3] = r.w;
            }
        } else { // 3
            const u16* A = (const u16*)p.Ap + (size_t)bz * p.sA;
            #pragma unroll
            for (int h = 0; h < 2; ++h) {
                const int g = tid + h * 256, k = g >> 4, m4 = (g & 15) * 4;
                const ushort4 r = *(const ushort4*)(A + (size_t)(k0 + k) * p.lda + m0 + m4);
                As[k][m4]=bf2f(r.x); As[k][m4+1]=bf2f(r.y); As[k][m4+2]=bf2f(r.z); As[k][m4+3]=bf2f(r.w);
            }
        }
        if (p.blay == 0) {
            const float* B = (const float*)p.Bp + (size_t)bz * p.sB;
            #pragma unroll
            for (int h = 0; h < 2; ++h) {
                const int g = tid + h * 256, k = g >> 4, n4 = (g & 15) * 4;
                const float4 r = *(const float4*)(B + (size_t)(k0 + k) * p.ldb + n0 + n4);
                Bs[k][n4] = r.x; Bs[k][n4+1] = r.y; Bs[k][n4+2] = r.z; Bs[k][n4+3] = r.w;
            }
        } else if (p.blay == 2) {
            const u16* B = (const u16*)p.Bp + (size_t)bz * p.sB;
            #pragma unroll
            for (int h = 0; h < 2; ++h) {
                const int g = tid + h * 256, k = g >> 4, n4 = (g & 15) * 4;
                const ushort4 r = *(const ushort4*)(B + (size_t)(k0 + k) * p.ldb + n0 + n4);
                Bs[k][n4]=bf2f(r.x); Bs[k][n4+1]=bf2f(r.y); Bs[k][n4+2]=bf2f(r.z); Bs[k][n4+3]=bf2f(r.w);
            }
        } else if (p.blay == 1) {
            const float* B = (const float*)p.Bp + (size_t)bz * p.sB;
            #pragma unroll
            for (int h = 0; h < 2; ++h) {
                const int g = tid + h * 256, n = g >> 3, k4 = (g & 7) * 4;
                const float4 r = *(const float4*)(B + (size_t)(n0 + n) * p.ldb + k0 + k4);
                Bs[k4][n] = r.x; Bs[k4+1][n] = r.y; Bs[k4+2][n] = r.z; Bs[k4+3][n] = r.w;
            }
        } else { // 3
            const u16* B = (const u16*)p.Bp + (size_t)bz * p.sB;
            #pragma unroll
            for (int h = 0; h < 2; ++h) {
                const int g = tid + h * 256, n = g >> 3, k4 = (g & 7) * 4;
                const ushort4 r = *(const ushort4*)(B + (size_t)(n0 + n) * p.ldb + k0 + k4);
                Bs[k4][n]=bf2f(r.x); Bs[k4+1][n]=bf2f(r.y); Bs[k4+2][n]=bf2f(r.z); Bs[k4+3][n]=bf2f(r.w);
            }
        }
        __syncthreads();
        #pragma unroll
        for (int kk = 0; kk < 32; ++kk) {
            const float4 xa = *(const float4*)&As[kk][ty * 4];
            const float4 wb = *(const float4*)&Bs[kk][tx * 4];
            const float xv[4] = {xa.x, xa.y, xa.z, xa.w};
            const float wv[4] = {wb.x, wb.y, wb.z, wb.w};
            #pragma unroll
            for (int i = 0; i < 4; ++i)
                #pragma unroll
                for (int j = 0; j < 4; ++j)
                    acc[i][j] = fmaf(xv[i], wv[j], acc[i][j]);
        }
        __syncthreads();
    }
    const int mb = m0 + ty * 4, nb = n0 + tx * 4;
    if (p.epi == 0) {
        float* C = (float*)p.Cp + (size_t)bz * p.sC;
        #pragma unroll
        for (int i = 0; i < 4; ++i)
            #pragma unroll
            for (int j = 0; j < 4; ++j)
                C[(size_t)(mb + i) * p.ldc + nb + j] = acc[i][j];
    } else if (p.epi == 3) {
        u16* O = (u16*)p.Cp + (size_t)bz * p.sC;
        const float* OB = p.Cio + (size_t)bz * p.sCio;
        #pragma unroll
        for (int i = 0; i < 4; ++i)
            #pragma unroll
            for (int j = 0; j < 4; ++j)
                O[(size_t)(mb + i) * p.ldc + nb + j] =
                    f2bf(acc[i][j] + OB[(size_t)(nb + j) * 256 + mb + i]);
    } else { // 4: Z/Zs hi+lo bf16, Alphab bf16, AlphaT bf16
        const size_t o0 = (size_t)bz * 65536;
        #pragma unroll
        for (int j = 0; j < 4; ++j) {
            const int n = nb + j;
            const float iv = p.invdp[bz * 128 + n];
            const float cav = p.cap[bz * 128 + n];
            const float cbv = p.cbp[bz * 128 + n];
            #pragma unroll
            for (int i = 0; i < 4; ++i) {
                const int m = mb + i;
                const float z = acc[i][j];
                const float zs = z * iv;
                float a = z * cav;
                if (cbv != 0.f) a = fmaf(cbv, bf2f(p.Ulastp[(size_t)bz * 1048576 + m]), a);
                const size_t o = o0 + (size_t)m * 128 + n;
                const u16 zh = f2bf(z);
                p.zhi[o] = zh; p.zlo[o] = f2bf(z - bf2f(zh));
                const u16 sh = f2bf(zs);
                p.zshi[o] = sh; p.zslo[o] = f2bf(zs - bf2f(sh));
                p.alb[o] = f2bf(a);
                p.albt[o0 + (size_t)n * 512 + m] = f2bf(a);
            }
        }
    }
}

__global__ __launch_bounds__(256) void gemmx(GP p) { gemm_body(p, blockIdx.z); }

// ---------------- merged level-5: MFMA K6 + MFMA gram3 (P, Ga, Gv) ----------------
__global__ __launch_bounds__(256)
void lvl5_kernel(const u16* Sb, const u16* AlT,
                 const u16* Qt, const u16* Vnt,
                 float* P, float* Ga, float* Gv, float* OBSA, float* dsum)
{
    const int z = blockIdx.z;
    if (z < 8) {
        mfk6_body(Sb, Qt, AlT, Vnt, OBSA, dsum, z);
        return;
    }
    if (blockIdx.x != 0 || blockIdx.y != 0) return;
    const int zz = z - 8, b = zz / 3, j = zz - b * 3;
    const u16* Ab = (j == 2) ? (Vnt + (size_t)b * 1048576) : (AlT + (size_t)b * 65536);
    const u16* Bb = (j == 0) ? (Qt + (size_t)b * 1048576)
                  : (j == 1) ? (AlT + (size_t)b * 65536)
                             : (Vnt + (size_t)b * 1048576);
    float* Cq = ((j == 0) ? P : (j == 1) ? Ga : Gv) + (size_t)b * 16384;
    mfg_body(Ab, Bb, Cq);
}

// ---------------- guard_tr: K8 (z<8) + guard (z 8-15) + VnT transpose (z 16-23) ----------------
__global__ __launch_bounds__(256)
void guard_tr_kernel(const float* __restrict__ dsum_g, const float* __restrict__ Ga,
                     const float* __restrict__ Gv, float* __restrict__ SnSq,
                     float* __restrict__ AnAcc, float* __restrict__ gdiag,
                     const float* __restrict__ P, const u16* __restrict__ Vnt,
                     u16* __restrict__ Obt, const float* __restrict__ OBSA,
                     u16* __restrict__ VnTc)
{
    const int z = blockIdx.z, tid = threadIdx.x;
    if (z < 8) {
        // K8: O = maskedP^T x Vn + OB -> Ob bf16 (grid x<2, y<8 native)
        GP p{};
        p.alay = 4; p.Ap = P; p.lda = 128; p.sA = 16384;
        p.blay = 2; p.Bp = Vnt; p.ldb = 512; p.sB = 1048576;
        p.epi = 3; p.Cp = Obt; p.ldc = 512; p.sC = 1048576;
        p.Cio = (float*)OBSA; p.sCio = 131072; p.K = 128;
        gemm_body(p, z);
        return;
    }
    if (z < 16) {
        if (blockIdx.x != 0 || blockIdx.y != 0) return;
        const int b = z - 8;
        __shared__ float rpart[256], dsh[128], mdia[128];
        const int t = tid & 127, half = tid >> 7;
        const float* gv = Gv + (size_t)b * 16384 + t * 128;
        const float* ga = Ga + (size_t)b * 16384 + t * 128;
        float rs = 0.f;
        for (int j = half; j < t; j += 2) rs = fmaf(gv[j], ga[j], rs);
        rpart[tid] = rs;
        if (half == 0) { dsh[t] = dsum_g[b * 128 + t]; mdia[t] = gv[t] * ga[t]; }
        __syncthreads();
        if (tid == 0) {
            const float An2 = AnAcc[b];
            float Sn2 = SnSq[b], D = 0.f, T = 0.f;
            int ng = 0;
            for (int t2 = 0; t2 < 128; ++t2) {
                D += dsh[t2];
                T += mdia[t2] + 2.f * (rpart[t2] + rpart[t2 + 128]);
                const float sn2 = Sn2 + 2.f * D + T;
                if (sn2 > 1e6f || An2 > 1e6f) ++ng;
            }
            SnSq[b] = Sn2 + 2.f * D + T;
            gdiag[b] = 1e-6f + (float)ng * 1e-5f;
            AnAcc[b] = 0.f;
        }
        return;
    }
    // transpose: VnTc[b][d][t] = Vnt[b][t][d], d-slab = blockIdx.y*128
    if (blockIdx.x != 0 || blockIdx.y >= 4) return;
    const int b = z - 16, d0 = blockIdx.y * 128;
    __shared__ u16 tile[64][65];
    const u16* Vn = Vnt + (size_t)b * 1048576;
    u16* VT = VnTc + (size_t)b * 65536;
    const int c = tid & 63, rbase = tid >> 6;
    for (int sd = 0; sd < 2; ++sd) {
        for (int st = 0; st < 2; ++st) {
            #pragma unroll
            for (int rr = 0; rr < 16; ++rr) {
                const int r = rbase + rr * 4;      // t offset
                tile[r][c] = Vn[(size_t)(st * 64 + r) * 512 + d0 + sd * 64 + c];
            }
            __syncthreads();
            #pragma unroll
            for (int rr = 0; rr < 16; ++rr) {
                const int r2 = rbase + rr * 4;     // d offset
                VT[(size_t)(d0 + sd * 64 + r2) * 128 + st * 64 + c] = tile[c][r2];
            }
            __syncthreads();
        }
    }
}

// ---------------- symmetric LDL^T elimination + level-doubling triangular inverse ----------------
__global__ __launch_bounds__(512)
void elim_kernel(const float* __restrict__ G, float* __restrict__ Tg,
                 const float* __restrict__ sseq, float* __restrict__ invd,
                 float* __restrict__ ca, float* __restrict__ cb,
                 float* __restrict__ dsum_g, const int t0)
{
    const int b = blockIdx.x, tid = threadIdx.x, lane = tid & 63, wave = tid >> 6;
    __shared__ __align__(16) float E[128][132];
    __shared__ __align__(16) float Cs[128][132];
    __shared__ __align__(16) float Scr[2368];
    __shared__ float del[128];
    float (*Tm)[132] = E;
    float (*LpT)[132] = (float(*)[132])Scr;
    float (*SpT)[132] = (float(*)[132])(Scr + 1056);

    {
        const float4* Gb = (const float4*)(G + (size_t)b * 16384);
        for (int idx = tid; idx < 4096; idx += ETH) {
            const int r = idx >> 5, c4 = idx & 31;
            ((float4*)&E[r][0])[c4] = Gb[idx];
        }
    }
    if (tid < 128) dsum_g[b * 128 + tid] = 0.f;
    __syncthreads();

    for (int p = 0; p < 16; ++p) {
        const int pc0 = p * 8;
        if (wave == 0) {
            float pr0[8], pr1[8];
            #pragma unroll
            for (int j = 0; j < 8; ++j) {
                pr0[j] = E[pc0 + j][lane];
                pr1[j] = E[pc0 + j][64 + lane];
            }
            float dl[8];
            const bool hi = (pc0 >= 64);
            #pragma unroll
            for (int j = 0; j < 8; ++j) {
                const int t = pc0 + j;
                const int pl = t & 63;
                float prow[8];
                #pragma unroll
                for (int c = 0; c < 8; ++c) {
                    const float v0 = __shfl(pr0[c], pl);
                    const float v1 = __shfl(pr1[c], pl);
                    prow[c] = hi ? v1 : v0;
                }
                const float d = fmaxf(1.f + prow[j], 1e-6f);
                dl[j] = d;
                const float inv = 1.f / d;
                if (lane > t) {
                    const float coef = pr0[j] * inv;
                    #pragma unroll
                    for (int c = j + 1; c < 8; ++c) pr0[c] = fmaf(-coef, prow[c], pr0[c]);
                }
                if (lane + 64 > t) {
                    const float coef = pr1[j] * inv;
                    #pragma unroll
                    for (int c = j + 1; c < 8; ++c) pr1[c] = fmaf(-coef, prow[c], pr1[c]);
                }
            }
            #pragma unroll
            for (int j = 0; j < 8; ++j) {
                const float idj = 1.f / dl[j];
                const int t = pc0 + j;
                {
                    const bool below = (lane > t);
                    const float y = below ? pr0[j] : 0.f;
                    const float l = y * idj;
                    LpT[j][lane] = l; SpT[j][lane] = y; Cs[t][lane] = l;
                }
                {
                    const int r = lane + 64;
                    const bool below = (r > t);
                    const float y = below ? pr1[j] : 0.f;
                    const float l = y * idj;
                    LpT[j][r] = l; SpT[j][r] = y; Cs[t][r] = l;
                }
            }
            if (lane < 8) del[pc0 + lane] = dl[lane];
        }
        __syncthreads();
        const int r0b = pc0 + 8;
        if (r0b < 128) {
            const int nrows = 128 - r0b;
            const int c40 = r0b >> 2, nc4 = 32 - c40;
            for (int idx = tid; idx < nrows * nc4; idx += ETH) {
                const int rr = idx / nc4, cc = idx - rr * nc4;
                const int r = r0b + rr, c4 = c40 + cc;
                float4 e = ((float4*)&E[r][0])[c4];
                #pragma unroll
                for (int j = 0; j < 8; ++j) {
                    const float lv = LpT[j][r];
                    const float4 sv = ((const float4*)&SpT[j][0])[c4];
                    e.x = fmaf(-lv, sv.x, e.x);
                    e.y = fmaf(-lv, sv.y, e.y);
                    e.z = fmaf(-lv, sv.z, e.z);
                    e.w = fmaf(-lv, sv.w, e.w);
                }
                ((float4*)&E[r][0])[c4] = e;
            }
        }
        __syncthreads();
    }

    for (int idx = tid; idx < 4224; idx += ETH)
        ((float4*)&Tm[0][0])[idx] = make_float4(0.f, 0.f, 0.f, 0.f);
    __syncthreads();
    if (tid < 128) Tm[tid][tid] = 1.f;
    __syncthreads();
    {
        const int g = tid >> 3, c = tid & 7;
        if (g < 16) {
            for (int r2 = c - 1; r2 >= 0; --r2) {
                float s = 0.f;
                for (int kk = r2 + 1; kk <= c; ++kk)
                    s = fmaf(Cs[8 * g + r2][8 * g + kk],
                             (kk == c) ? 1.f : Tm[8 * g + kk][8 * g + c], s);
                Tm[8 * g + r2][8 * g + c] = -s;
            }
        }
    }
    __syncthreads();
    for (int s = 8; s <= 64; s <<= 1) {
        const int npairs = 64 / s;
        const int nj = (s == 64) ? 32 : s;
        const int stride = nj + 4;
        const int nj4 = nj >> 2;
        const int Nel = npairs * s * nj4;
        const int nhalf = (s == 64) ? 2 : 1;
        for (int jh = 0; jh < nhalf; ++jh) {
            for (int idx = tid; idx < Nel; idx += ETH) {
                const int p2 = idx / (s * nj4), rem = idx - p2 * s * nj4;
                const int i = rem / nj4, j4 = rem - i * nj4;
                const int I0 = 2 * s * p2, J0 = I0 + s;
                const int jc = j4 * 4 + jh * 32;
                float4 x = make_float4(0.f, 0.f, 0.f, 0.f);
                for (int k = 0; k < s; ++k) {
                    const float cv = Cs[I0 + i][J0 + k];
                    const float4 tv = *(const float4*)&Tm[J0 + k][J0 + jc];
                    x.x = fmaf(cv, tv.x, x.x);
                    x.y = fmaf(cv, tv.y, x.y);
                    x.z = fmaf(cv, tv.z, x.z);
                    x.w = fmaf(cv, tv.w, x.w);
                }
                *(float4*)&Scr[p2 * s * stride + i * stride + j4 * 4] = x;
            }
            __syncthreads();
            for (int idx = tid; idx < Nel; idx += ETH) {
                const int p2 = idx / (s * nj4), rem = idx - p2 * s * nj4;
                const int i = rem / nj4, j4 = rem - i * nj4;
                const int I0 = 2 * s * p2, J0 = I0 + s;
                const int jc = j4 * 4 + jh * 32;
                float4 y = make_float4(0.f, 0.f, 0.f, 0.f);
                for (int k = 0; k < s; ++k) {
                    const float tv = Tm[I0 + i][I0 + k];
                    const float4 xv = *(const float4*)&Scr[p2 * s * stride + k * stride + j4 * 4];
                    y.x = fmaf(tv, xv.x, y.x);
                    y.y = fmaf(tv, xv.y, y.y);
                    y.z = fmaf(tv, xv.z, y.z);
                    y.w = fmaf(tv, xv.w, y.w);
                }
                float4 o;
                o.x = -y.x; o.y = -y.y; o.z = -y.z; o.w = -y.w;
                *(float4*)&Tm[I0 + i][J0 + jc] = o;
            }
            __syncthreads();
        }
    }
    {
        float4* Tgb = (float4*)(Tg + (size_t)b * 16384);
        for (int idx = tid; idx < 4096; idx += ETH) {
            const int r = idx >> 5, c4 = idx & 31;
            Tgb[idx] = ((const float4*)&Tm[r][0])[c4];
        }
    }
    if (tid < 128) {
        const float d = del[tid];
        const float s = sseq[(size_t)b * TT + t0 + tid];
        invd[b * 128 + tid] = 1.f / d;
        ca[b * 128 + tid] = s / d;
        cb[b * 128 + tid] = (tid == 127) ? s * 1e-6f : 0.f;
    }
}

extern "C" void kernel_launch(void* const* d_in, const int* in_sizes, int n_in,
                              void* d_out, int out_size, void* d_ws, size_t ws_size,
                              hipStream_t stream)
{
    const float* x  = (const float*)d_in[0];
    const float* Wq = (const float*)d_in[1];
    const float* bq = (const float*)d_in[2];
    const float* Wk = (const float*)d_in[3];
    const float* bk = (const float*)d_in[4];
    const float* Wv = (const float*)d_in[5];
    const float* bv = (const float*)d_in[6];
    const float* Wo = (const float*)d_in[7];
    const float* bo = (const float*)d_in[8];

    char* ws = (char*)d_ws;
    u16* Qb    = (u16*)(ws);
    u16* Ub    = (u16*)(ws + (16ull << 20));
    u16* Vnb   = (u16*)(ws + (32ull << 20));
    u16* Ob    = (u16*)(ws + (48ull << 20));   // also x_bf before chunk loop
    u16* x_bf  = Ob;
    float* A    = (float*)(ws + (64ull << 20));
    float* S    = (float*)(ws + (72ull << 20));
    float* Wm   = (float*)(ws + (80ull << 20));
    u16* Zhi   = (u16*)(ws + (82ull << 20));   // 1 MiB each, [b][512][128] bf16
    u16* Zlo   = (u16*)(ws + (83ull << 20));
    u16* Zshi  = (u16*)(ws + (84ull << 20));
    u16* Zslo  = (u16*)(ws + (85ull << 20));
    u16* Alphab= (u16*)(ws + (86ull << 20));
    u16* VnTc  = (u16*)(ws + (87ull << 20));   // 1 MiB [b][512][128] bf16 chunk transpose
    float* OBSA = (float*)(ws + (88ull << 20));
    float* G    = (float*)(ws + (92ull << 20));
    float* Tg   = (float*)(ws + (92ull << 20) + (512ull << 10));
    float* P    = (float*)(ws + (93ull << 20));
    float* Ga   = (float*)(ws + (93ull << 20) + (512ull << 10));
    float* Gv   = (float*)(ws + (94ull << 20));
    float* invd = (float*)(ws + (94ull << 20) + (512ull << 10));
    float* ca   = (float*)(ws + (94ull << 20) + (516ull << 10));
    float* cb   = (float*)(ws + (94ull << 20) + (520ull << 10));
    float* sseq = (float*)(ws + (94ull << 20) + (528ull << 10));
    float* SnSq = (float*)(ws + (94ull << 20) + (600ull << 10));
    float* AnAcc= (float*)(ws + (94ull << 20) + (600ull << 10) + 64);
    float* gdiag= (float*)(ws + (94ull << 20) + (600ull << 10) + 128);
    float* dsum = (float*)(ws + (94ull << 20) + (604ull << 10));
    u16* Wq_bf = (u16*)(ws + (95ull << 20));
    u16* Wk_bf = (u16*)(ws + (95ull << 20) + (512ull << 10));
    u16* Wv_bf = (u16*)(ws + (96ull << 20));
    u16* Wo_bf = (u16*)(ws + (96ull << 20) + (512ull << 10));
    u16* S_bf  = (u16*)(ws + (97ull << 20));   // 4 MiB bf16 mirror of S
    u16* AlT   = (u16*)(ws + (101ull << 20));  // 1 MiB AlphaT bf16

    const bool big = (ws_size >= (111ull << 20));
    u16* A_bf = big ? (u16*)(ws + (102ull << 20)) : (u16*)nullptr;  // 8 MiB

    f2bf_kernel<<<2048, 256, 0, stream>>>((const float4*)x, (ushort4*)x_bf, 2097152);
    wconv_kernel<<<dim3(256, 4), 256, 0, stream>>>(
        (const float4*)Wq, (const float4*)Wk, (const float4*)Wv, (const float4*)Wo,
        (ushort4*)Wq_bf, (ushort4*)Wk_bf, (ushort4*)Wv_bf, (ushort4*)Wo_bf);

    mfma_gemm<1><<<dim3(128, 4), 256, 0, stream>>>(x_bf, Wq_bf, bq, Qb, 1.f);
    mfma_gemm<1><<<dim3(128, 4), 256, 0, stream>>>(x_bf, Wk_bf, bk, Ub, 0.04419417382415922f);
    mfma_gemm<1><<<dim3(128, 4), 256, 0, stream>>>(x_bf, Wv_bf, bv, Vnb, 1.f);
    prep_kernel<<<4096, 256, 0, stream>>>(Qb, Ub, Vnb, sseq);
    init_kernel<<<2048, 256, 0, stream>>>((float4*)A, (float4*)S, (ushort4*)S_bf,
                                          (ushort4*)A_bf, SnSq, AnAcc);

    for (int c = 0; c < NC; ++c) {
        const int t0 = c * LL;
        const u16* Ut = Ub + (size_t)t0 * 512;
        const u16* Qt = Qb + (size_t)t0 * 512;
        const u16* Vt = Vnb + (size_t)t0 * 512;
        // K1: W = A x U^T (MFMA via A_bf when workspace allows, vector fallback)
        if (big) {
            mfk1_kernel<<<dim3(4, 1, 8), 256, 0, stream>>>(A_bf, Ut, Wm);
        } else {
            GP p1{}; p1.alay = 0; p1.Ap = A; p1.lda = 512; p1.sA = 262144;
            p1.blay = 3; p1.Bp = Ut; p1.ldb = 512; p1.sB = 1048576;
            p1.epi = 0; p1.Cp = Wm; p1.ldc = 128; p1.sC = 65536; p1.K = 512;
            gemmx<<<dim3(8, 2, 8), 256, 0, stream>>>(p1);
        }
        // K2: G = U^T W
        GP p2{}; p2.alay = 2; p2.Ap = Ut; p2.lda = 512; p2.sA = 1048576;
        p2.blay = 0; p2.Bp = Wm; p2.ldb = 128; p2.sB = 65536;
        p2.epi = 0; p2.Cp = G; p2.ldc = 128; p2.sC = 16384; p2.K = 512;
        gemmx<<<dim3(2, 2, 8), 256, 0, stream>>>(p2);
        elim_kernel<<<8, 512, 0, stream>>>(G, Tg, sseq, invd, ca, cb, dsum, t0);
        // p4: Z/Zs hi+lo bf16, Alphab bf16, AlphaT bf16 = W x T with scale epilogue
        GP p4{}; p4.alay = 0; p4.Ap = Wm; p4.lda = 128; p4.sA = 65536;
        p4.blay = 0; p4.Bp = Tg; p4.ldb = 128; p4.sB = 16384;
        p4.epi = 4;
        p4.zhi = Zhi; p4.zlo = Zlo; p4.zshi = Zshi; p4.zslo = Zslo;
        p4.alb = Alphab; p4.albt = AlT;
        p4.invdp = invd; p4.cap = ca; p4.cbp = cb;
        p4.Ulastp = Ub + (size_t)(t0 + 127) * 512;
        p4.K = 128; p4.ldc = 128;
        gemmx<<<dim3(8, 2, 8), 256, 0, stream>>>(p4);
        // lvl5: MFMA K6 (OBSA + dsum) + MFMA gram3 (P, Ga, Gv)
        lvl5_kernel<<<dim3(4, 2, 32), 256, 0, stream>>>(S_bf, AlT, Qt, Vt,
            P, Ga, Gv, OBSA, dsum);
        // guard_tr: K8 (O out) + guard + VnT chunk transpose
        guard_tr_kernel<<<dim3(2, 8, 24), 256, 0, stream>>>(dsum, Ga, Gv, SnSq, AnAcc,
            gdiag, P, Vt, Ob + (size_t)t0 * 512, OBSA, VnTc);
        // lvl7a: MFMA K10 (A update, split bf16) + MFMA K9 (S update)
        lvl7a_kernel<<<dim3(4, 4, 16), 256, 0, stream>>>(Zshi, Zslo, Zhi, Zlo,
            A, A_bf, gdiag, AnAcc, VnTc, Alphab, S, S_bf);
    }
    mfma_gemm<0><<<dim3(128, 4), 256, 0, stream>>>(Ob, Wo_bf, bo, d_out, 1.f);
}